// Round 2
// baseline (1941.906 us; speedup 1.0000x reference)
//
#include <hip/hip_runtime.h>
#include <hip/hip_bf16.h>

#define DEV static __device__ __forceinline__

DEV float sigm(float x) { return 1.f / (1.f + __expf(-x)); }

// Edge tables from ADJ nonzeros: (src, dst) pairs in np.nonzero order
__constant__ int d_esrc[10] = {0,1,1,1,2,2,3,4,4,5};
// incoming edges per node (dst == node)
__constant__ int d_inc[6][3] = {{1,-1,-1},{0,4,7},{2,6,-1},{5,-1,-1},{3,9,-1},{8,-1,-1}};
__constant__ int d_ne[6] = {1,3,2,1,2,1};

// ---------------------------------------------------------------------------
// Weight prep: transpose fp32 weights so inner-loop weight addresses are
// block-uniform (scalar loads).
//   src layout: [e][OC][C][3][3] (flat index == thread id)
//   dst layout: tap_major=0: [e][C][9][OC]   (offset convs)
//               tap_major=1: [e][9][C][OC]   (main dfconv einsum weights)
// ---------------------------------------------------------------------------
__global__ void prep_w(const float* __restrict__ src, float* __restrict__ dst,
                       int OC, int C, int tap_major, int total) {
  int i = blockIdx.x * 256 + threadIdx.x;
  if (i >= total) return;
  int t = i % 9; int n = i / 9;
  int c = n % C; n /= C;
  int oc = n % OC; int e = n / OC;
  float v = src[i];
  int inner = tap_major ? (t * C + c) : (c * 9 + t);
  dst[(e * C * 9 + inner) * OC + oc] = v;
}

// ---------------------------------------------------------------------------
// Offset conv 1: 3x3 SAME conv, input = concat(p_fea[256], xp[src][10]),
// out channels 27, output o1[e][27][9216].
// ---------------------------------------------------------------------------
__global__ __launch_bounds__(256) void offconv1_k(
    const float* __restrict__ pfea, const float* __restrict__ xp,
    const float* __restrict__ wf, const float* __restrict__ ob,
    float* __restrict__ o1) {
  const int e = blockIdx.y;
  const int p = blockIdx.x * 256 + threadIdx.x;
  const int y = p / 96, x = p % 96;
  const int a = d_esrc[e];
  float acc[27];
#pragma unroll
  for (int oc = 0; oc < 27; ++oc) acc[oc] = ob[e * 27 + oc];
  int offs[9]; float vmask[9];
#pragma unroll
  for (int t = 0; t < 9; ++t) {
    int yy = y + t / 3 - 1, xx = x + t % 3 - 1;
    bool ok = (yy >= 0) && (yy < 96) && (xx >= 0) && (xx < 96);
    int yc = min(max(yy, 0), 95), xc = min(max(xx, 0), 95);
    offs[t] = yc * 96 + xc;
    vmask[t] = ok ? 1.f : 0.f;
  }
  for (int c = 0; c < 266; ++c) {
    const float* ptr = (c < 256) ? (pfea + c * 9216)
                                 : (xp + (a * 10 + (c - 256)) * 9216);
    float xv[9];
#pragma unroll
    for (int t = 0; t < 9; ++t) xv[t] = vmask[t] * ptr[offs[t]];
    const float* wc = wf + (e * 266 + c) * 243;  // [9][27], block-uniform
#pragma unroll
    for (int t = 0; t < 9; ++t) {
      float v = xv[t];
#pragma unroll
      for (int oc = 0; oc < 27; ++oc)
        acc[oc] = fmaf(v, wc[t * 27 + oc], acc[oc]);
    }
  }
#pragma unroll
  for (int oc = 0; oc < 27; ++oc) o1[(e * 27 + oc) * 9216 + p] = acc[oc];
}

// Offset conv 2: input = h1 [e][20][9216], out o2[e][27][9216]
__global__ __launch_bounds__(256) void offconv2_k(
    const float* __restrict__ h1, const float* __restrict__ wf,
    const float* __restrict__ ob, float* __restrict__ o2) {
  const int e = blockIdx.y;
  const int p = blockIdx.x * 256 + threadIdx.x;
  const int y = p / 96, x = p % 96;
  float acc[27];
#pragma unroll
  for (int oc = 0; oc < 27; ++oc) acc[oc] = ob[e * 27 + oc];
  int offs[9]; float vmask[9];
#pragma unroll
  for (int t = 0; t < 9; ++t) {
    int yy = y + t / 3 - 1, xx = x + t % 3 - 1;
    bool ok = (yy >= 0) && (yy < 96) && (xx >= 0) && (xx < 96);
    int yc = min(max(yy, 0), 95), xc = min(max(xx, 0), 95);
    offs[t] = yc * 96 + xc;
    vmask[t] = ok ? 1.f : 0.f;
  }
  for (int c = 0; c < 20; ++c) {
    const float* ptr = h1 + (e * 20 + c) * 9216;
    float xv[9];
#pragma unroll
    for (int t = 0; t < 9; ++t) xv[t] = vmask[t] * ptr[offs[t]];
    const float* wc = wf + (e * 20 + c) * 243;
#pragma unroll
    for (int t = 0; t < 9; ++t) {
      float v = xv[t];
#pragma unroll
      for (int oc = 0; oc < 27; ++oc)
        acc[oc] = fmaf(v, wc[t * 27 + oc], acc[oc]);
    }
  }
#pragma unroll
  for (int oc = 0; oc < 27; ++oc) o2[(e * 27 + oc) * 9216 + p] = acc[oc];
}

// ---------------------------------------------------------------------------
// Deformable-conv main 1: bilinear-sample concat input at offset taps, einsum
// with wm1[e][tap][266][20], affine(s1,b1)+relu -> h1[e][20][9216].
// ---------------------------------------------------------------------------
__global__ __launch_bounds__(256) void dfmain1_k(
    const float* __restrict__ pfea, const float* __restrict__ xp,
    const float* __restrict__ o1, const float* __restrict__ wm,
    const float* __restrict__ s, const float* __restrict__ b,
    float* __restrict__ hout) {
  const int e = blockIdx.y;
  const int p = blockIdx.x * 256 + threadIdx.x;
  const int y = p / 96, x = p % 96;
  const int a = d_esrc[e];
  int io[9][4]; float cw[9][4];
#pragma unroll
  for (int k = 0; k < 9; ++k) {
    float offy = o1[(e * 27 + 2 * k) * 9216 + p];
    float offx = o1[(e * 27 + 2 * k + 1) * 9216 + p];
    float m = sigm(o1[(e * 27 + 18 + k) * 9216 + p]);
    float py = (float)(y + k / 3 - 1) + offy;
    float px = (float)(x + k % 3 - 1) + offx;
    float y0 = floorf(py), x0 = floorf(px);
    float wy = py - y0, wx = px - x0;
    int iy0 = (int)y0, ix0 = (int)x0;
#pragma unroll
    for (int dy = 0; dy < 2; ++dy)
#pragma unroll
      for (int dx = 0; dx < 2; ++dx) {
        float yi = y0 + dy, xi = x0 + dx;
        bool ok = (yi >= 0.f) && (yi < 96.f) && (xi >= 0.f) && (xi < 96.f);
        int yc = min(max(iy0 + dy, 0), 95), xc = min(max(ix0 + dx, 0), 95);
        io[k][dy * 2 + dx] = yc * 96 + xc;
        cw[k][dy * 2 + dx] =
            (ok ? m : 0.f) * (dy ? wy : (1.f - wy)) * (dx ? wx : (1.f - wx));
      }
  }
  float acc[20];
#pragma unroll
  for (int oc = 0; oc < 20; ++oc) acc[oc] = 0.f;
  for (int c = 0; c < 266; ++c) {
    const float* ptr = (c < 256) ? (pfea + c * 9216)
                                 : (xp + (a * 10 + (c - 256)) * 9216);
#pragma unroll
    for (int k = 0; k < 9; ++k) {
      float sv = cw[k][0] * ptr[io[k][0]] + cw[k][1] * ptr[io[k][1]] +
                 cw[k][2] * ptr[io[k][2]] + cw[k][3] * ptr[io[k][3]];
      const float* wc = wm + ((e * 9 + k) * 266 + c) * 20;  // block-uniform
#pragma unroll
      for (int oc = 0; oc < 20; ++oc) acc[oc] = fmaf(sv, wc[oc], acc[oc]);
    }
  }
#pragma unroll
  for (int oc = 0; oc < 20; ++oc) {
    float v = s[e * 20 + oc] * acc[oc] + b[e * 20 + oc];
    hout[(e * 20 + oc) * 9216 + p] = fmaxf(v, 0.f);
  }
}

// Deformable-conv main 2: input h1 (20 ch), out h2[e][10][9216]
__global__ __launch_bounds__(256) void dfmain2_k(
    const float* __restrict__ h1, const float* __restrict__ o2,
    const float* __restrict__ wm, const float* __restrict__ s,
    const float* __restrict__ b, float* __restrict__ hout) {
  const int e = blockIdx.y;
  const int p = blockIdx.x * 256 + threadIdx.x;
  const int y = p / 96, x = p % 96;
  int io[9][4]; float cw[9][4];
#pragma unroll
  for (int k = 0; k < 9; ++k) {
    float offy = o2[(e * 27 + 2 * k) * 9216 + p];
    float offx = o2[(e * 27 + 2 * k + 1) * 9216 + p];
    float m = sigm(o2[(e * 27 + 18 + k) * 9216 + p]);
    float py = (float)(y + k / 3 - 1) + offy;
    float px = (float)(x + k % 3 - 1) + offx;
    float y0 = floorf(py), x0 = floorf(px);
    float wy = py - y0, wx = px - x0;
    int iy0 = (int)y0, ix0 = (int)x0;
#pragma unroll
    for (int dy = 0; dy < 2; ++dy)
#pragma unroll
      for (int dx = 0; dx < 2; ++dx) {
        float yi = y0 + dy, xi = x0 + dx;
        bool ok = (yi >= 0.f) && (yi < 96.f) && (xi >= 0.f) && (xi < 96.f);
        int yc = min(max(iy0 + dy, 0), 95), xc = min(max(ix0 + dx, 0), 95);
        io[k][dy * 2 + dx] = yc * 96 + xc;
        cw[k][dy * 2 + dx] =
            (ok ? m : 0.f) * (dy ? wy : (1.f - wy)) * (dx ? wx : (1.f - wx));
      }
  }
  float acc[10];
#pragma unroll
  for (int oc = 0; oc < 10; ++oc) acc[oc] = 0.f;
  for (int c = 0; c < 20; ++c) {
    const float* ptr = h1 + (e * 20 + c) * 9216;
#pragma unroll
    for (int k = 0; k < 9; ++k) {
      float sv = cw[k][0] * ptr[io[k][0]] + cw[k][1] * ptr[io[k][1]] +
                 cw[k][2] * ptr[io[k][2]] + cw[k][3] * ptr[io[k][3]];
      const float* wc = wm + ((e * 9 + k) * 20 + c) * 10;
#pragma unroll
      for (int oc = 0; oc < 10; ++oc) acc[oc] = fmaf(sv, wc[oc], acc[oc]);
    }
  }
#pragma unroll
  for (int oc = 0; oc < 10; ++oc) {
    float v = s[e * 10 + oc] * acc[oc] + b[e * 10 + oc];
    hout[(e * 10 + oc) * 9216 + p] = fmaxf(v, 0.f);
  }
}

// ---------------------------------------------------------------------------
// Node message stage: xpp (attention-weighted max over incoming edges)
// + xhp (attention-gated 1x1 conv of p_fea) -> msgs (written to d_out part 1)
// ---------------------------------------------------------------------------
__global__ __launch_bounds__(256) void msg_k(
    const float* __restrict__ pfea, const float* __restrict__ xp,
    const float* __restrict__ xh, const float* __restrict__ h2,
    const float* __restrict__ aw, const float* __restrict__ ab,
    const float* __restrict__ bw, const float* __restrict__ bb,
    const float* __restrict__ w1, const float* __restrict__ s1,
    const float* __restrict__ b1, const float* __restrict__ w2,
    const float* __restrict__ b2, const float* __restrict__ wfh,
    const float* __restrict__ sfh, const float* __restrict__ bfh,
    float* __restrict__ msgs) {
  const int j = blockIdx.y;
  const int p = blockIdx.x * 256 + threadIdx.x;
  float xj[10];
#pragma unroll
  for (int c = 0; c < 10; ++c) xj[c] = xp[(j * 10 + c) * 9216 + p];
  float xpp[10];
  int ne = d_ne[j];
  for (int ei = 0; ei < ne; ++ei) {
    int e = d_inc[j][ei];
    int a2 = d_esrc[e];
    float sA = ab[e];
#pragma unroll
    for (int c = 0; c < 10; ++c)
      sA = fmaf(xp[(a2 * 10 + c) * 9216 + p], aw[e * 10 + c], sA);
    float sB = bb[e];
#pragma unroll
    for (int c = 0; c < 10; ++c) sB = fmaf(xj[c], bw[e * 10 + c], sB);
    float f = (1.f - sigm(sA)) * sigm(sB);
#pragma unroll
    for (int c = 0; c < 10; ++c) {
      float m = f * h2[(e * 10 + c) * 9216 + p];
      xpp[c] = (ei == 0) ? m : fmaxf(xpp[c], m);
    }
  }
  const float* hf = xh + ((j < 4) ? 0 : 1) * 10 * 9216;
  float cat[20];
#pragma unroll
  for (int c = 0; c < 10; ++c) cat[c] = hf[c * 9216 + p];
#pragma unroll
  for (int c = 0; c < 10; ++c) cat[10 + c] = xj[c];
  float at = b2[j];
#pragma unroll
  for (int oc = 0; oc < 20; ++oc) {
    float t = 0.f;
#pragma unroll
    for (int c = 0; c < 20; ++c)
      t = fmaf(cat[c], w1[(j * 20 + oc) * 20 + c], t);
    float av = fmaxf(s1[j * 20 + oc] * t + b1[j * 20 + oc], 0.f);
    at = fmaf(av, w2[j * 20 + oc], at);
  }
  at = sigm(at);
  float accf[10];
#pragma unroll
  for (int c = 0; c < 10; ++c) accf[c] = 0.f;
  for (int ci = 0; ci < 256; ++ci) {
    float pv = pfea[ci * 9216 + p];
#pragma unroll
    for (int c = 0; c < 10; ++c)
      accf[c] = fmaf(pv, wfh[(j * 10 + c) * 256 + ci], accf[c]);
  }
#pragma unroll
  for (int c = 0; c < 10; ++c) {
    float xhp = fmaxf(sfh[j * 10 + c] * (at * accf[c]) + bfh[j * 10 + c], 0.f);
    msgs[(j * 10 + c) * 9216 + p] = xpp[c] + xhp;
  }
}

// ---------------------------------------------------------------------------
// GRU stage. h0 == 0, so gh == bhh (per-channel constants) and z*h term
// vanishes: h = (1-z) * tanh(i_n + r*bhh_n),  r/z from sigmoid(i_* + bhh_*).
// ---------------------------------------------------------------------------
__global__ __launch_bounds__(256) void gru_k(
    const float* __restrict__ xp, const float* __restrict__ msgs,
    const float* __restrict__ wih1, const float* __restrict__ bih1,
    const float* __restrict__ bhh1, const float* __restrict__ wih2,
    const float* __restrict__ bih2, const float* __restrict__ bhh2,
    float* __restrict__ out) {
  const int j = blockIdx.y;
  const int p = blockIdx.x * 256 + threadIdx.x;
  float xin[20];
#pragma unroll
  for (int c = 0; c < 10; ++c) xin[c] = xp[(j * 10 + c) * 9216 + p];
#pragma unroll
  for (int c = 0; c < 10; ++c) xin[10 + c] = msgs[(j * 10 + c) * 9216 + p];
  float gi[30];
#pragma unroll
  for (int r = 0; r < 30; ++r) gi[r] = bih1[j * 30 + r];
  for (int c = 0; c < 20; ++c) {
    float v = xin[c];
#pragma unroll
    for (int r = 0; r < 30; ++r)
      gi[r] = fmaf(v, wih1[(j * 30 + r) * 20 + c], gi[r]);
  }
  float h1v[10];
#pragma unroll
  for (int c = 0; c < 10; ++c) {
    float r = sigm(gi[c] + bhh1[j * 30 + c]);
    float z = sigm(gi[10 + c] + bhh1[j * 30 + 10 + c]);
    float n = tanhf(gi[20 + c] + r * bhh1[j * 30 + 20 + c]);
    h1v[c] = (1.f - z) * n;
  }
  float g2[30];
#pragma unroll
  for (int r = 0; r < 30; ++r) g2[r] = bih2[j * 30 + r];
  for (int c = 0; c < 10; ++c) {
    float v = h1v[c];
#pragma unroll
    for (int r = 0; r < 30; ++r)
      g2[r] = fmaf(v, wih2[(j * 30 + r) * 10 + c], g2[r]);
  }
#pragma unroll
  for (int c = 0; c < 10; ++c) {
    float r = sigm(g2[c] + bhh2[j * 30 + c]);
    float z = sigm(g2[10 + c] + bhh2[j * 30 + 10 + c]);
    float n = tanhf(g2[20 + c] + r * bhh2[j * 30 + 20 + c]);
    out[(j * 10 + c) * 9216 + p] = (1.f - z) * n;
  }
}

extern "C" void kernel_launch(void* const* d_in, const int* in_sizes, int n_in,
                              void* d_out, int out_size, void* d_ws, size_t ws_size,
                              hipStream_t stream) {
  const float* pfea   = (const float*)d_in[0];
  const float* xp     = (const float*)d_in[1];
  const float* xh     = (const float*)d_in[2];
  const float* dp_ow1 = (const float*)d_in[3];
  const float* dp_ob1 = (const float*)d_in[4];
  const float* dp_w1  = (const float*)d_in[5];
  const float* dp_s1  = (const float*)d_in[6];
  const float* dp_b1  = (const float*)d_in[7];
  const float* dp_ow2 = (const float*)d_in[8];
  const float* dp_ob2 = (const float*)d_in[9];
  const float* dp_w2  = (const float*)d_in[10];
  const float* dp_s2  = (const float*)d_in[11];
  const float* dp_b2  = (const float*)d_in[12];
  const float* dp_aw  = (const float*)d_in[13];
  const float* dp_ab  = (const float*)d_in[14];
  const float* dp_bw  = (const float*)d_in[15];
  const float* dp_bb  = (const float*)d_in[16];
  const float* dc_w1  = (const float*)d_in[17];
  const float* dc_s1  = (const float*)d_in[18];
  const float* dc_b1  = (const float*)d_in[19];
  const float* dc_w2  = (const float*)d_in[20];
  const float* dc_b2  = (const float*)d_in[21];
  const float* dc_wfh = (const float*)d_in[22];
  const float* dc_sfh = (const float*)d_in[23];
  const float* dc_bfh = (const float*)d_in[24];
  const float* g_wih1 = (const float*)d_in[25];
  const float* g_bih1 = (const float*)d_in[26];
  const float* g_bhh1 = (const float*)d_in[28];
  const float* g_wih2 = (const float*)d_in[29];
  const float* g_bih2 = (const float*)d_in[30];
  const float* g_bhh2 = (const float*)d_in[32];

  float* ws  = (float*)d_ws;
  float* wf1 = ws;             // 10*266*9*27  = 646380
  float* wf2 = wf1 + 646380;   // 10*20*9*27   = 48600
  float* wm1 = wf2 + 48600;    // 10*9*266*20  = 478800
  float* wm2 = wm1 + 478800;   // 10*9*20*10   = 18000
  float* o1  = wm2 + 18000;    // 10*27*9216   = 2488320 (o2 aliases o1)
  float* o2  = o1;             //   o1 dead after dfmain1_k
  float* h1  = o1 + 2488320;   // 10*20*9216   = 1843200
  float* h2  = h1 + 1843200;   // 10*10*9216   = 921600
  // total ws: 6,444,900 floats = 25.8 MB

  float* out_x = (float*)d_out;        // xp_out: 6*10*9216
  float* out_m = out_x + 552960;       // msgs:   6*10*9216 (written by msg_k)

  prep_w<<<dim3((646380 + 255) / 256), 256, 0, stream>>>(dp_ow1, wf1, 27, 266, 0, 646380);
  prep_w<<<dim3((48600 + 255) / 256), 256, 0, stream>>>(dp_ow2, wf2, 27, 20, 0, 48600);
  prep_w<<<dim3((478800 + 255) / 256), 256, 0, stream>>>(dp_w1, wm1, 20, 266, 1, 478800);
  prep_w<<<dim3((18000 + 255) / 256), 256, 0, stream>>>(dp_w2, wm2, 10, 20, 1, 18000);

  dim3 blk(256);
  dim3 gE(36, 10);
  offconv1_k<<<gE, blk, 0, stream>>>(pfea, xp, wf1, dp_ob1, o1);
  dfmain1_k<<<gE, blk, 0, stream>>>(pfea, xp, o1, wm1, dp_s1, dp_b1, h1);
  offconv2_k<<<gE, blk, 0, stream>>>(h1, wf2, dp_ob2, o2);
  dfmain2_k<<<gE, blk, 0, stream>>>(h1, o2, wm2, dp_s2, dp_b2, h2);

  dim3 gN(36, 6);
  msg_k<<<gN, blk, 0, stream>>>(pfea, xp, xh, h2, dp_aw, dp_ab, dp_bw, dp_bb,
                                dc_w1, dc_s1, dc_b1, dc_w2, dc_b2,
                                dc_wfh, dc_sfh, dc_bfh, out_m);
  gru_k<<<gN, blk, 0, stream>>>(xp, out_m, g_wih1, g_bih1, g_bhh1,
                                g_wih2, g_bih2, g_bhh2, out_x);
}

// Round 3
// 1057.135 us; speedup vs baseline: 1.8370x; 1.8370x over previous
//
#include <hip/hip_runtime.h>
#include <hip/hip_bf16.h>

#define DEV static __device__ __forceinline__

DEV float sigm(float x) { return 1.f / (1.f + __expf(-x)); }

// Edge tables from ADJ nonzeros: (src, dst) pairs in np.nonzero order
__constant__ int d_esrc[10] = {0,1,1,1,2,2,3,4,4,5};
// incoming edges per node (dst == node)
__constant__ int d_inc[6][3] = {{1,-1,-1},{0,4,7},{2,6,-1},{5,-1,-1},{3,9,-1},{8,-1,-1}};
__constant__ int d_ne[6] = {1,3,2,1,2,1};

// ---------------------------------------------------------------------------
// Weight prep: transpose fp32 weights so inner-loop weight addresses are
// block-uniform (scalar loads).
//   src layout: [e][OC][C][3][3]
//   dst layout: tap_major=0: [e][C][9][OC]   (offset convs)
//               tap_major=1: [e][9][C][OC]   (main dfconv einsum weights)
// ---------------------------------------------------------------------------
__global__ void prep_w(const float* __restrict__ src, float* __restrict__ dst,
                       int OC, int C, int tap_major, int total) {
  int i = blockIdx.x * 256 + threadIdx.x;
  if (i >= total) return;
  int t = i % 9; int n = i / 9;
  int c = n % C; n /= C;
  int oc = n % OC; int e = n / OC;
  float v = src[i];
  int inner = tap_major ? (t * C + c) : (c * 9 + t);
  dst[(e * C * 9 + inner) * OC + oc] = v;
}

// Broadcast per-channel bias into o1[e][27][9216]
__global__ void init_o1_k(const float* __restrict__ ob, float* __restrict__ o1) {
  int i = blockIdx.x * 256 + threadIdx.x;   // total 10*27*9216
  o1[i] = ob[i / 9216];
}

// ---------------------------------------------------------------------------
// Offset conv 1 (split-K over channels, atomic accumulate into o1).
// grid (36, 10, 4)
// ---------------------------------------------------------------------------
__global__ __launch_bounds__(256) void offconv1_k(
    const float* __restrict__ pfea, const float* __restrict__ xp,
    const float* __restrict__ wf, float* __restrict__ o1) {
  const int e = blockIdx.y;
  const int z = blockIdx.z;
  const int p = blockIdx.x * 256 + threadIdx.x;
  const int y = p / 96, x = p % 96;
  const int a = d_esrc[e];
  const int c_lo = (z * 266) / 4, c_hi = ((z + 1) * 266) / 4;
  float acc[27];
#pragma unroll
  for (int oc = 0; oc < 27; ++oc) acc[oc] = 0.f;
  int offs[9]; float vmask[9];
#pragma unroll
  for (int t = 0; t < 9; ++t) {
    int yy = y + t / 3 - 1, xx = x + t % 3 - 1;
    bool ok = (yy >= 0) && (yy < 96) && (xx >= 0) && (xx < 96);
    int yc = min(max(yy, 0), 95), xc = min(max(xx, 0), 95);
    offs[t] = yc * 96 + xc;
    vmask[t] = ok ? 1.f : 0.f;
  }
  for (int c = c_lo; c < c_hi; ++c) {
    const float* ptr = (c < 256) ? (pfea + c * 9216)
                                 : (xp + (a * 10 + (c - 256)) * 9216);
    float xv[9];
#pragma unroll
    for (int t = 0; t < 9; ++t) xv[t] = vmask[t] * ptr[offs[t]];
    const float* wc = wf + (e * 266 + c) * 243;  // [9][27], block-uniform
#pragma unroll
    for (int t = 0; t < 9; ++t) {
      float v = xv[t];
#pragma unroll
      for (int oc = 0; oc < 27; ++oc)
        acc[oc] = fmaf(v, wc[t * 27 + oc], acc[oc]);
    }
  }
#pragma unroll
  for (int oc = 0; oc < 27; ++oc)
    atomicAdd(&o1[(e * 27 + oc) * 9216 + p], acc[oc]);
}

// ---------------------------------------------------------------------------
// Deformable-conv main 1 (split-K, atomic accumulate into h1acc).
// grid (36, 10, 4)
// ---------------------------------------------------------------------------
__global__ __launch_bounds__(256) void dfmain1_k(
    const float* __restrict__ pfea, const float* __restrict__ xp,
    const float* __restrict__ o1, const float* __restrict__ wm,
    float* __restrict__ hacc) {
  const int e = blockIdx.y;
  const int z = blockIdx.z;
  const int p = blockIdx.x * 256 + threadIdx.x;
  const int y = p / 96, x = p % 96;
  const int a = d_esrc[e];
  const int c_lo = (z * 266) / 4, c_hi = ((z + 1) * 266) / 4;
  int io[9][4]; float cw[9][4];
#pragma unroll
  for (int k = 0; k < 9; ++k) {
    float offy = o1[(e * 27 + 2 * k) * 9216 + p];
    float offx = o1[(e * 27 + 2 * k + 1) * 9216 + p];
    float m = sigm(o1[(e * 27 + 18 + k) * 9216 + p]);
    float py = (float)(y + k / 3 - 1) + offy;
    float px = (float)(x + k % 3 - 1) + offx;
    float y0 = floorf(py), x0 = floorf(px);
    float wy = py - y0, wx = px - x0;
    int iy0 = (int)y0, ix0 = (int)x0;
#pragma unroll
    for (int dy = 0; dy < 2; ++dy)
#pragma unroll
      for (int dx = 0; dx < 2; ++dx) {
        float yi = y0 + dy, xi = x0 + dx;
        bool ok = (yi >= 0.f) && (yi < 96.f) && (xi >= 0.f) && (xi < 96.f);
        int yc = min(max(iy0 + dy, 0), 95), xc = min(max(ix0 + dx, 0), 95);
        io[k][dy * 2 + dx] = yc * 96 + xc;
        cw[k][dy * 2 + dx] =
            (ok ? m : 0.f) * (dy ? wy : (1.f - wy)) * (dx ? wx : (1.f - wx));
      }
  }
  float acc[20];
#pragma unroll
  for (int oc = 0; oc < 20; ++oc) acc[oc] = 0.f;
  for (int c = c_lo; c < c_hi; ++c) {
    const float* ptr = (c < 256) ? (pfea + c * 9216)
                                 : (xp + (a * 10 + (c - 256)) * 9216);
#pragma unroll
    for (int k = 0; k < 9; ++k) {
      float sv = cw[k][0] * ptr[io[k][0]] + cw[k][1] * ptr[io[k][1]] +
                 cw[k][2] * ptr[io[k][2]] + cw[k][3] * ptr[io[k][3]];
      const float* wc = wm + ((e * 9 + k) * 266 + c) * 20;  // block-uniform
#pragma unroll
      for (int oc = 0; oc < 20; ++oc) acc[oc] = fmaf(sv, wc[oc], acc[oc]);
    }
  }
#pragma unroll
  for (int oc = 0; oc < 20; ++oc)
    atomicAdd(&hacc[(e * 20 + oc) * 9216 + p], acc[oc]);
}

// In-place h1 = relu(s * h1acc + b); total 10*20*9216
__global__ void fin_h1_k(float* __restrict__ h1, const float* __restrict__ s,
                         const float* __restrict__ b) {
  int i = blockIdx.x * 256 + threadIdx.x;
  int ch = i / 9216;
  h1[i] = fmaxf(fmaf(s[ch], h1[i], b[ch]), 0.f);
}

// Offset conv 2: input = h1 [e][20][9216], out o2[e][27][9216] (direct+bias)
__global__ __launch_bounds__(256) void offconv2_k(
    const float* __restrict__ h1, const float* __restrict__ wf,
    const float* __restrict__ ob, float* __restrict__ o2) {
  const int e = blockIdx.y;
  const int p = blockIdx.x * 256 + threadIdx.x;
  const int y = p / 96, x = p % 96;
  float acc[27];
#pragma unroll
  for (int oc = 0; oc < 27; ++oc) acc[oc] = ob[e * 27 + oc];
  int offs[9]; float vmask[9];
#pragma unroll
  for (int t = 0; t < 9; ++t) {
    int yy = y + t / 3 - 1, xx = x + t % 3 - 1;
    bool ok = (yy >= 0) && (yy < 96) && (xx >= 0) && (xx < 96);
    int yc = min(max(yy, 0), 95), xc = min(max(xx, 0), 95);
    offs[t] = yc * 96 + xc;
    vmask[t] = ok ? 1.f : 0.f;
  }
  for (int c = 0; c < 20; ++c) {
    const float* ptr = h1 + (e * 20 + c) * 9216;
    float xv[9];
#pragma unroll
    for (int t = 0; t < 9; ++t) xv[t] = vmask[t] * ptr[offs[t]];
    const float* wc = wf + (e * 20 + c) * 243;
#pragma unroll
    for (int t = 0; t < 9; ++t) {
      float v = xv[t];
#pragma unroll
      for (int oc = 0; oc < 27; ++oc)
        acc[oc] = fmaf(v, wc[t * 27 + oc], acc[oc]);
    }
  }
#pragma unroll
  for (int oc = 0; oc < 27; ++oc) o2[(e * 27 + oc) * 9216 + p] = acc[oc];
}

// Deformable-conv main 2: input h1 (20 ch), out h2[e][10][9216] (affine+relu)
__global__ __launch_bounds__(256) void dfmain2_k(
    const float* __restrict__ h1, const float* __restrict__ o2,
    const float* __restrict__ wm, const float* __restrict__ s,
    const float* __restrict__ b, float* __restrict__ hout) {
  const int e = blockIdx.y;
  const int p = blockIdx.x * 256 + threadIdx.x;
  const int y = p / 96, x = p % 96;
  int io[9][4]; float cw[9][4];
#pragma unroll
  for (int k = 0; k < 9; ++k) {
    float offy = o2[(e * 27 + 2 * k) * 9216 + p];
    float offx = o2[(e * 27 + 2 * k + 1) * 9216 + p];
    float m = sigm(o2[(e * 27 + 18 + k) * 9216 + p]);
    float py = (float)(y + k / 3 - 1) + offy;
    float px = (float)(x + k % 3 - 1) + offx;
    float y0 = floorf(py), x0 = floorf(px);
    float wy = py - y0, wx = px - x0;
    int iy0 = (int)y0, ix0 = (int)x0;
#pragma unroll
    for (int dy = 0; dy < 2; ++dy)
#pragma unroll
      for (int dx = 0; dx < 2; ++dx) {
        float yi = y0 + dy, xi = x0 + dx;
        bool ok = (yi >= 0.f) && (yi < 96.f) && (xi >= 0.f) && (xi < 96.f);
        int yc = min(max(iy0 + dy, 0), 95), xc = min(max(ix0 + dx, 0), 95);
        io[k][dy * 2 + dx] = yc * 96 + xc;
        cw[k][dy * 2 + dx] =
            (ok ? m : 0.f) * (dy ? wy : (1.f - wy)) * (dx ? wx : (1.f - wx));
      }
  }
  float acc[10];
#pragma unroll
  for (int oc = 0; oc < 10; ++oc) acc[oc] = 0.f;
  for (int c = 0; c < 20; ++c) {
    const float* ptr = h1 + (e * 20 + c) * 9216;
#pragma unroll
    for (int k = 0; k < 9; ++k) {
      float sv = cw[k][0] * ptr[io[k][0]] + cw[k][1] * ptr[io[k][1]] +
                 cw[k][2] * ptr[io[k][2]] + cw[k][3] * ptr[io[k][3]];
      const float* wc = wm + ((e * 9 + k) * 20 + c) * 10;
#pragma unroll
      for (int oc = 0; oc < 10; ++oc) acc[oc] = fmaf(sv, wc[oc], acc[oc]);
    }
  }
#pragma unroll
  for (int oc = 0; oc < 10; ++oc) {
    float v = s[e * 10 + oc] * acc[oc] + b[e * 10 + oc];
    hout[(e * 10 + oc) * 9216 + p] = fmaxf(v, 0.f);
  }
}

// 1x1 conv p_fea (256ch) -> accfh[j][10][9216], split-K atomic. grid (36,6,4)
__global__ __launch_bounds__(256) void conv_fh_k(
    const float* __restrict__ pfea, const float* __restrict__ wfh,
    float* __restrict__ accfh) {
  const int j = blockIdx.y;
  const int z = blockIdx.z;
  const int p = blockIdx.x * 256 + threadIdx.x;
  const int c_lo = z * 64;
  float acc[10];
#pragma unroll
  for (int c = 0; c < 10; ++c) acc[c] = 0.f;
  for (int ci = c_lo; ci < c_lo + 64; ++ci) {
    float pv = pfea[ci * 9216 + p];
#pragma unroll
    for (int c = 0; c < 10; ++c)
      acc[c] = fmaf(pv, wfh[(j * 10 + c) * 256 + ci], acc[c]);
  }
#pragma unroll
  for (int c = 0; c < 10; ++c)
    atomicAdd(&accfh[(j * 10 + c) * 9216 + p], acc[c]);
}

// ---------------------------------------------------------------------------
// Node message stage (light now): xpp + attention-gated precomputed conv
// ---------------------------------------------------------------------------
__global__ __launch_bounds__(256) void msg_k(
    const float* __restrict__ xp, const float* __restrict__ xh,
    const float* __restrict__ h2, const float* __restrict__ accfh,
    const float* __restrict__ aw, const float* __restrict__ ab,
    const float* __restrict__ bw, const float* __restrict__ bb,
    const float* __restrict__ w1, const float* __restrict__ s1,
    const float* __restrict__ b1, const float* __restrict__ w2,
    const float* __restrict__ b2, const float* __restrict__ sfh,
    const float* __restrict__ bfh, float* __restrict__ msgs) {
  const int j = blockIdx.y;
  const int p = blockIdx.x * 256 + threadIdx.x;
  float xj[10];
#pragma unroll
  for (int c = 0; c < 10; ++c) xj[c] = xp[(j * 10 + c) * 9216 + p];
  float xpp[10];
  int ne = d_ne[j];
  for (int ei = 0; ei < ne; ++ei) {
    int e = d_inc[j][ei];
    int a2 = d_esrc[e];
    float sA = ab[e];
#pragma unroll
    for (int c = 0; c < 10; ++c)
      sA = fmaf(xp[(a2 * 10 + c) * 9216 + p], aw[e * 10 + c], sA);
    float sB = bb[e];
#pragma unroll
    for (int c = 0; c < 10; ++c) sB = fmaf(xj[c], bw[e * 10 + c], sB);
    float f = (1.f - sigm(sA)) * sigm(sB);
#pragma unroll
    for (int c = 0; c < 10; ++c) {
      float m = f * h2[(e * 10 + c) * 9216 + p];
      xpp[c] = (ei == 0) ? m : fmaxf(xpp[c], m);
    }
  }
  const float* hf = xh + ((j < 4) ? 0 : 1) * 10 * 9216;
  float cat[20];
#pragma unroll
  for (int c = 0; c < 10; ++c) cat[c] = hf[c * 9216 + p];
#pragma unroll
  for (int c = 0; c < 10; ++c) cat[10 + c] = xj[c];
  float at = b2[j];
#pragma unroll
  for (int oc = 0; oc < 20; ++oc) {
    float t = 0.f;
#pragma unroll
    for (int c = 0; c < 20; ++c)
      t = fmaf(cat[c], w1[(j * 20 + oc) * 20 + c], t);
    float av = fmaxf(s1[j * 20 + oc] * t + b1[j * 20 + oc], 0.f);
    at = fmaf(av, w2[j * 20 + oc], at);
  }
  at = sigm(at);
#pragma unroll
  for (int c = 0; c < 10; ++c) {
    float xhp = fmaxf(sfh[j * 10 + c] * (at * accfh[(j * 10 + c) * 9216 + p]) +
                          bfh[j * 10 + c], 0.f);
    msgs[(j * 10 + c) * 9216 + p] = xpp[c] + xhp;
  }
}

// ---------------------------------------------------------------------------
// GRU stage. h0 == 0 => gh == bhh constants; z*h term vanishes.
// ---------------------------------------------------------------------------
__global__ __launch_bounds__(256) void gru_k(
    const float* __restrict__ xp, const float* __restrict__ msgs,
    const float* __restrict__ wih1, const float* __restrict__ bih1,
    const float* __restrict__ bhh1, const float* __restrict__ wih2,
    const float* __restrict__ bih2, const float* __restrict__ bhh2,
    float* __restrict__ out) {
  const int j = blockIdx.y;
  const int p = blockIdx.x * 256 + threadIdx.x;
  float xin[20];
#pragma unroll
  for (int c = 0; c < 10; ++c) xin[c] = xp[(j * 10 + c) * 9216 + p];
#pragma unroll
  for (int c = 0; c < 10; ++c) xin[10 + c] = msgs[(j * 10 + c) * 9216 + p];
  float gi[30];
#pragma unroll
  for (int r = 0; r < 30; ++r) gi[r] = bih1[j * 30 + r];
  for (int c = 0; c < 20; ++c) {
    float v = xin[c];
#pragma unroll
    for (int r = 0; r < 30; ++r)
      gi[r] = fmaf(v, wih1[(j * 30 + r) * 20 + c], gi[r]);
  }
  float h1v[10];
#pragma unroll
  for (int c = 0; c < 10; ++c) {
    float r = sigm(gi[c] + bhh1[j * 30 + c]);
    float z = sigm(gi[10 + c] + bhh1[j * 30 + 10 + c]);
    float n = tanhf(gi[20 + c] + r * bhh1[j * 30 + 20 + c]);
    h1v[c] = (1.f - z) * n;
  }
  float g2[30];
#pragma unroll
  for (int r = 0; r < 30; ++r) g2[r] = bih2[j * 30 + r];
  for (int c = 0; c < 10; ++c) {
    float v = h1v[c];
#pragma unroll
    for (int r = 0; r < 30; ++r)
      g2[r] = fmaf(v, wih2[(j * 30 + r) * 10 + c], g2[r]);
  }
#pragma unroll
  for (int c = 0; c < 10; ++c) {
    float r = sigm(g2[c] + bhh2[j * 30 + c]);
    float z = sigm(g2[10 + c] + bhh2[j * 30 + 10 + c]);
    float n = tanhf(g2[20 + c] + r * bhh2[j * 30 + 20 + c]);
    out[(j * 10 + c) * 9216 + p] = (1.f - z) * n;
  }
}

extern "C" void kernel_launch(void* const* d_in, const int* in_sizes, int n_in,
                              void* d_out, int out_size, void* d_ws, size_t ws_size,
                              hipStream_t stream) {
  const float* pfea   = (const float*)d_in[0];
  const float* xp     = (const float*)d_in[1];
  const float* xh     = (const float*)d_in[2];
  const float* dp_ow1 = (const float*)d_in[3];
  const float* dp_ob1 = (const float*)d_in[4];
  const float* dp_w1  = (const float*)d_in[5];
  const float* dp_s1  = (const float*)d_in[6];
  const float* dp_b1  = (const float*)d_in[7];
  const float* dp_ow2 = (const float*)d_in[8];
  const float* dp_ob2 = (const float*)d_in[9];
  const float* dp_w2  = (const float*)d_in[10];
  const float* dp_s2  = (const float*)d_in[11];
  const float* dp_b2  = (const float*)d_in[12];
  const float* dp_aw  = (const float*)d_in[13];
  const float* dp_ab  = (const float*)d_in[14];
  const float* dp_bw  = (const float*)d_in[15];
  const float* dp_bb  = (const float*)d_in[16];
  const float* dc_w1  = (const float*)d_in[17];
  const float* dc_s1  = (const float*)d_in[18];
  const float* dc_b1  = (const float*)d_in[19];
  const float* dc_w2  = (const float*)d_in[20];
  const float* dc_b2  = (const float*)d_in[21];
  const float* dc_wfh = (const float*)d_in[22];
  const float* dc_sfh = (const float*)d_in[23];
  const float* dc_bfh = (const float*)d_in[24];
  const float* g_wih1 = (const float*)d_in[25];
  const float* g_bih1 = (const float*)d_in[26];
  const float* g_bhh1 = (const float*)d_in[28];
  const float* g_wih2 = (const float*)d_in[29];
  const float* g_bih2 = (const float*)d_in[30];
  const float* g_bhh2 = (const float*)d_in[32];

  float* ws  = (float*)d_ws;
  float* wf1 = ws;             // 646380 (dead after offconv1; accfh reuses)
  float* accfh = ws;           //   6*10*9216 = 552960 <= 646380
  float* wf2 = wf1 + 646380;   // 48600
  float* wm1 = wf2 + 48600;    // 478800
  float* wm2 = wm1 + 478800;   // 18000
  float* o1  = wm2 + 18000;    // 2488320 (o2 aliases after dfmain1)
  float* o2  = o1;
  float* h1  = o1 + 2488320;   // 1843200
  float* h2  = h1 + 1843200;   // 921600
  // total ws: 6,444,900 floats = 25.78 MB (same footprint as round 2)

  float* out_x = (float*)d_out;        // xp_out: 6*10*9216
  float* out_m = out_x + 552960;       // msgs:   6*10*9216

  prep_w<<<dim3((646380 + 255) / 256), 256, 0, stream>>>(dp_ow1, wf1, 27, 266, 0, 646380);
  prep_w<<<dim3((48600 + 255) / 256), 256, 0, stream>>>(dp_ow2, wf2, 27, 20, 0, 48600);
  prep_w<<<dim3((478800 + 255) / 256), 256, 0, stream>>>(dp_w1, wm1, 20, 266, 1, 478800);
  prep_w<<<dim3((18000 + 255) / 256), 256, 0, stream>>>(dp_w2, wm2, 10, 20, 1, 18000);

  init_o1_k<<<dim3(2488320 / 256), 256, 0, stream>>>(dp_ob1, o1);
  hipMemsetAsync(h1, 0, 1843200 * sizeof(float), stream);

  dim3 blk(256);
  offconv1_k<<<dim3(36, 10, 4), blk, 0, stream>>>(pfea, xp, wf1, o1);
  dfmain1_k<<<dim3(36, 10, 4), blk, 0, stream>>>(pfea, xp, o1, wm1, h1);
  fin_h1_k<<<dim3(1843200 / 256), blk, 0, stream>>>(h1, dp_s1, dp_b1);

  offconv2_k<<<dim3(36, 10), blk, 0, stream>>>(h1, wf2, dp_ob2, o2);
  dfmain2_k<<<dim3(36, 10), blk, 0, stream>>>(h1, o2, wm2, dp_s2, dp_b2, h2);

  hipMemsetAsync(accfh, 0, 552960 * sizeof(float), stream);
  conv_fh_k<<<dim3(36, 6, 4), blk, 0, stream>>>(pfea, dc_wfh, accfh);

  msg_k<<<dim3(36, 6), blk, 0, stream>>>(xp, xh, h2, accfh,
                                         dp_aw, dp_ab, dp_bw, dp_bb,
                                         dc_w1, dc_s1, dc_b1, dc_w2, dc_b2,
                                         dc_sfh, dc_bfh, out_m);
  gru_k<<<dim3(36, 6), blk, 0, stream>>>(xp, out_m, g_wih1, g_bih1, g_bhh1,
                                         g_wih2, g_bih2, g_bhh2, out_x);
}

// Round 4
// 769.731 us; speedup vs baseline: 2.5228x; 1.3734x over previous
//
#include <hip/hip_runtime.h>
#include <hip/hip_bf16.h>

#define DEV static __device__ __forceinline__

DEV float sigm(float x) { return 1.f / (1.f + __expf(-x)); }

// Edge tables from ADJ nonzeros: (src, dst) pairs in np.nonzero order
__constant__ int d_esrc[10] = {0,1,1,1,2,2,3,4,4,5};
__constant__ int d_inc[6][3] = {{1,-1,-1},{0,4,7},{2,6,-1},{5,-1,-1},{3,9,-1},{8,-1,-1}};
__constant__ int d_ne[6] = {1,3,2,1,2,1};

// Tile geometry: 32x8 pixels per block, halo 4 -> staged 16 rows x 40 cols.
#define TW 32
#define TH 8
#define SW 40
#define SH 16
#define SN 640   // SW*SH

// ---------------------------------------------------------------------------
// Weight prep (transpose for block-uniform scalar loads).
//   src: [e][OC][C][3][3]
//   dst: tap_major=0: [e][C][9][OC]   tap_major=1: [e][9][C][OC]
// ---------------------------------------------------------------------------
__global__ void prep_w(const float* __restrict__ src, float* __restrict__ dst,
                       int OC, int C, int tap_major, int total) {
  int i = blockIdx.x * 256 + threadIdx.x;
  if (i >= total) return;
  int t = i % 9; int n = i / 9;
  int c = n % C; n /= C;
  int oc = n % OC; int e = n / OC;
  float v = src[i];
  int inner = tap_major ? (t * C + c) : (c * 9 + t);
  dst[(e * C * 9 + inner) * OC + oc] = v;
}

// Broadcast per-channel bias into o1[e][27][9216]
__global__ void init_o1_k(const float* __restrict__ ob, float* __restrict__ o1) {
  int i = blockIdx.x * 256 + threadIdx.x;
  o1[i] = ob[i / 9216];
}

// Staging-address precompute: element i of the 16x40 window, clamped.
DEV int stage_goff(int i, int ty0, int tx0) {
  int r = i / SW, cl = i % SW;
  int gy = min(max(ty0 - 4 + r, 0), 95);
  int gx = min(max(tx0 - 4 + cl, 0), 95);
  return gy * 96 + gx;
}

// ---------------------------------------------------------------------------
// Offset conv 1 (3x3 SAME, LDS-tiled, split-K, atomic). grid (10,36,4)
// input concat(pfea[256], xp[src][10]); out += into o1[e][27][9216]
// ---------------------------------------------------------------------------
__global__ __launch_bounds__(256) void offconv1_k(
    const float* __restrict__ pfea, const float* __restrict__ xp,
    const float* __restrict__ wf, float* __restrict__ o1) {
  __shared__ float sbuf[2][SN];
  const int e = blockIdx.x, m = blockIdx.y, z = blockIdx.z;
  const int tid = threadIdx.x;
  const int tx = tid % TW, ty = tid / TW;
  const int tx0 = (m % 3) * TW, ty0 = (m / 3) * TH;
  const int y = ty0 + ty, x = tx0 + tx;
  const int p = y * 96 + x;
  const float* xpe = xp + d_esrc[e] * 10 * 9216;
  const int c_lo = (z * 266) / 4, c_hi = ((z + 1) * 266) / 4;

  const int g0 = stage_goff(tid, ty0, tx0);
  const int g1 = stage_goff(tid + 256, ty0, tx0);
  const int g2 = (tid < SN - 512) ? stage_goff(tid + 512, ty0, tx0) : 0;

  float vmask[9];
#pragma unroll
  for (int t = 0; t < 9; ++t) {
    int yy = y + t / 3 - 1, xx = x + t % 3 - 1;
    vmask[t] = ((yy >= 0) && (yy < 96) && (xx >= 0) && (xx < 96)) ? 1.f : 0.f;
  }
  const int vbase = (ty + 3) * SW + (tx + 3);  // tap (-1,-1) element index

  float acc[27];
#pragma unroll
  for (int oc = 0; oc < 27; ++oc) acc[oc] = 0.f;

  const float* img = (c_lo < 256) ? (pfea + c_lo * 9216) : (xpe + (c_lo - 256) * 9216);
  float p0 = img[g0], p1 = img[g1], p2 = (tid < SN - 512) ? img[g2] : 0.f;

  for (int c = c_lo; c < c_hi; ++c) {
    float* buf = sbuf[c & 1];
    buf[tid] = p0; buf[tid + 256] = p1;
    if (tid < SN - 512) buf[tid + 512] = p2;
    if (c + 1 < c_hi) {
      const float* ni = (c + 1 < 256) ? (pfea + (c + 1) * 9216)
                                      : (xpe + (c + 1 - 256) * 9216);
      p0 = ni[g0]; p1 = ni[g1]; if (tid < SN - 512) p2 = ni[g2];
    }
    __syncthreads();
    const float* wc = wf + (e * 266 + c) * 243;  // [9][27] block-uniform
#pragma unroll
    for (int t = 0; t < 9; ++t) {
      float v = vmask[t] * buf[vbase + (t / 3) * SW + (t % 3)];
#pragma unroll
      for (int oc = 0; oc < 27; ++oc)
        acc[oc] = fmaf(v, wc[t * 27 + oc], acc[oc]);
    }
  }
#pragma unroll
  for (int oc = 0; oc < 27; ++oc)
    atomicAdd(&o1[(e * 27 + oc) * 9216 + p], acc[oc]);
}

// ---------------------------------------------------------------------------
// Deformable main conv 1 (LDS-tiled bilinear, split-K, atomic). grid (10,36,4)
// ---------------------------------------------------------------------------
__global__ __launch_bounds__(256) void dfmain1_k(
    const float* __restrict__ pfea, const float* __restrict__ xp,
    const float* __restrict__ o1, const float* __restrict__ wm,
    float* __restrict__ hacc) {
  __shared__ float sbuf[2][SN];
  const int e = blockIdx.x, m = blockIdx.y, z = blockIdx.z;
  const int tid = threadIdx.x;
  const int tx = tid % TW, ty = tid / TW;
  const int tx0 = (m % 3) * TW, ty0 = (m / 3) * TH;
  const int y = ty0 + ty, x = tx0 + tx;
  const int p = y * 96 + x;
  const float* xpe = xp + d_esrc[e] * 10 * 9216;
  const int c_lo = (z * 266) / 4, c_hi = ((z + 1) * 266) / 4;

  const int g0 = stage_goff(tid, ty0, tx0);
  const int g1 = stage_goff(tid + 256, ty0, tx0);
  const int g2 = (tid < SN - 512) ? stage_goff(tid + 512, ty0, tx0) : 0;

  // Per-tap corner setup from offsets
  int iob[9];        // element index of corner (0,0) in tile, clamped
  float cw[9][4];
  bool oob = false;
#pragma unroll
  for (int k = 0; k < 9; ++k) {
    float offy = o1[(e * 27 + 2 * k) * 9216 + p];
    float offx = o1[(e * 27 + 2 * k + 1) * 9216 + p];
    float mk = sigm(o1[(e * 27 + 18 + k) * 9216 + p]);
    float py = (float)(y + k / 3 - 1) + offy;
    float px = (float)(x + k % 3 - 1) + offx;
    float fy = floorf(py), fx = floorf(px);
    float wy = py - fy, wx = px - fx;
    int iy = (int)fy, ix = (int)fx;
#pragma unroll
    for (int dy = 0; dy < 2; ++dy)
#pragma unroll
      for (int dx = 0; dx < 2; ++dx) {
        bool ok = (iy + dy >= 0) && (iy + dy < 96) && (ix + dx >= 0) && (ix + dx < 96);
        cw[k][dy * 2 + dx] =
            (ok ? mk : 0.f) * (dy ? wy : (1.f - wy)) * (dx ? wx : (1.f - wx));
      }
    int ir = iy - (ty0 - 4), ic = ix - (tx0 - 4);
    oob |= ((unsigned)ir > (unsigned)(SH - 2)) | ((unsigned)ic > (unsigned)(SW - 2));
    iob[k] = min(max(ir, 0), SH - 2) * SW + min(max(ic, 0), SW - 2);
  }

  float acc[20];
#pragma unroll
  for (int oc = 0; oc < 20; ++oc) acc[oc] = 0.f;

  const float* img = (c_lo < 256) ? (pfea + c_lo * 9216) : (xpe + (c_lo - 256) * 9216);
  float p0 = img[g0], p1 = img[g1], p2 = (tid < SN - 512) ? img[g2] : 0.f;

  for (int c = c_lo; c < c_hi; ++c) {
    float* buf = sbuf[c & 1];
    buf[tid] = p0; buf[tid + 256] = p1;
    if (tid < SN - 512) buf[tid + 512] = p2;
    if (c + 1 < c_hi) {
      const float* ni = (c + 1 < 256) ? (pfea + (c + 1) * 9216)
                                      : (xpe + (c + 1 - 256) * 9216);
      p0 = ni[g0]; p1 = ni[g1]; if (tid < SN - 512) p2 = ni[g2];
    }
    __syncthreads();
#pragma unroll
    for (int k = 0; k < 9; ++k) {
      const float* bk = &sbuf[c & 1][iob[k]];
      float sv = cw[k][0] * bk[0] + cw[k][1] * bk[1] +
                 cw[k][2] * bk[SW] + cw[k][3] * bk[SW + 1];
      const float* wc = wm + ((e * 9 + k) * 266 + c) * 20;  // block-uniform
#pragma unroll
      for (int oc = 0; oc < 20; ++oc) acc[oc] = fmaf(sv, wc[oc], acc[oc]);
    }
  }

  // Per-lane slow path: offsets escaped the halo (recompute from scratch).
  if (oob) {
#pragma unroll
    for (int oc = 0; oc < 20; ++oc) acc[oc] = 0.f;
    for (int k = 0; k < 9; ++k) {
      float offy = o1[(e * 27 + 2 * k) * 9216 + p];
      float offx = o1[(e * 27 + 2 * k + 1) * 9216 + p];
      float mk = sigm(o1[(e * 27 + 18 + k) * 9216 + p]);
      float py = (float)(y + k / 3 - 1) + offy;
      float px = (float)(x + k % 3 - 1) + offx;
      float fy = floorf(py), fx = floorf(px);
      float wy = py - fy, wx = px - fx;
      int iy = (int)fy, ix = (int)fx;
      int go[4]; float gw[4];
#pragma unroll
      for (int dy = 0; dy < 2; ++dy)
#pragma unroll
        for (int dx = 0; dx < 2; ++dx) {
          bool ok = (iy + dy >= 0) && (iy + dy < 96) && (ix + dx >= 0) && (ix + dx < 96);
          int yc = min(max(iy + dy, 0), 95), xc = min(max(ix + dx, 0), 95);
          go[dy * 2 + dx] = yc * 96 + xc;
          gw[dy * 2 + dx] =
              (ok ? mk : 0.f) * (dy ? wy : (1.f - wy)) * (dx ? wx : (1.f - wx));
        }
      for (int c = c_lo; c < c_hi; ++c) {
        const float* ptr = (c < 256) ? (pfea + c * 9216) : (xpe + (c - 256) * 9216);
        float sv = gw[0] * ptr[go[0]] + gw[1] * ptr[go[1]] +
                   gw[2] * ptr[go[2]] + gw[3] * ptr[go[3]];
        const float* wc = wm + ((e * 9 + k) * 266 + c) * 20;
#pragma unroll
        for (int oc = 0; oc < 20; ++oc) acc[oc] = fmaf(sv, wc[oc], acc[oc]);
      }
    }
  }
#pragma unroll
  for (int oc = 0; oc < 20; ++oc)
    atomicAdd(&hacc[(e * 20 + oc) * 9216 + p], acc[oc]);
}

// In-place h1 = relu(s * h1acc + b)
__global__ void fin_h1_k(float* __restrict__ h1, const float* __restrict__ s,
                         const float* __restrict__ b) {
  int i = blockIdx.x * 256 + threadIdx.x;
  int ch = i / 9216;
  h1[i] = fmaxf(fmaf(s[ch], h1[i], b[ch]), 0.f);
}

// ---------------------------------------------------------------------------
// Offset conv 2 (3x3 SAME on h1, LDS-tiled, direct). grid (10,36)
// ---------------------------------------------------------------------------
__global__ __launch_bounds__(256) void offconv2_k(
    const float* __restrict__ h1, const float* __restrict__ wf,
    const float* __restrict__ ob, float* __restrict__ o2) {
  __shared__ float sbuf[2][SN];
  const int e = blockIdx.x, m = blockIdx.y;
  const int tid = threadIdx.x;
  const int tx = tid % TW, ty = tid / TW;
  const int tx0 = (m % 3) * TW, ty0 = (m / 3) * TH;
  const int y = ty0 + ty, x = tx0 + tx;
  const int p = y * 96 + x;

  const int g0 = stage_goff(tid, ty0, tx0);
  const int g1 = stage_goff(tid + 256, ty0, tx0);
  const int g2 = (tid < SN - 512) ? stage_goff(tid + 512, ty0, tx0) : 0;

  float vmask[9];
#pragma unroll
  for (int t = 0; t < 9; ++t) {
    int yy = y + t / 3 - 1, xx = x + t % 3 - 1;
    vmask[t] = ((yy >= 0) && (yy < 96) && (xx >= 0) && (xx < 96)) ? 1.f : 0.f;
  }
  const int vbase = (ty + 3) * SW + (tx + 3);

  float acc[27];
#pragma unroll
  for (int oc = 0; oc < 27; ++oc) acc[oc] = ob[e * 27 + oc];

  const float* base = h1 + e * 20 * 9216;
  float p0 = base[g0], p1 = base[g1], p2 = (tid < SN - 512) ? base[g2] : 0.f;

  for (int c = 0; c < 20; ++c) {
    float* buf = sbuf[c & 1];
    buf[tid] = p0; buf[tid + 256] = p1;
    if (tid < SN - 512) buf[tid + 512] = p2;
    if (c + 1 < 20) {
      const float* ni = base + (c + 1) * 9216;
      p0 = ni[g0]; p1 = ni[g1]; if (tid < SN - 512) p2 = ni[g2];
    }
    __syncthreads();
    const float* wc = wf + (e * 20 + c) * 243;
#pragma unroll
    for (int t = 0; t < 9; ++t) {
      float v = vmask[t] * buf[vbase + (t / 3) * SW + (t % 3)];
#pragma unroll
      for (int oc = 0; oc < 27; ++oc)
        acc[oc] = fmaf(v, wc[t * 27 + oc], acc[oc]);
    }
  }
#pragma unroll
  for (int oc = 0; oc < 27; ++oc) o2[(e * 27 + oc) * 9216 + p] = acc[oc];
}

// ---------------------------------------------------------------------------
// Deformable main conv 2 (LDS-tiled, direct, affine+relu). grid (10,36)
// ---------------------------------------------------------------------------
__global__ __launch_bounds__(256) void dfmain2_k(
    const float* __restrict__ h1, const float* __restrict__ o2,
    const float* __restrict__ wm, const float* __restrict__ s,
    const float* __restrict__ b, float* __restrict__ hout) {
  __shared__ float sbuf[2][SN];
  const int e = blockIdx.x, m = blockIdx.y;
  const int tid = threadIdx.x;
  const int tx = tid % TW, ty = tid / TW;
  const int tx0 = (m % 3) * TW, ty0 = (m / 3) * TH;
  const int y = ty0 + ty, x = tx0 + tx;
  const int p = y * 96 + x;
  const float* base = h1 + e * 20 * 9216;

  const int g0 = stage_goff(tid, ty0, tx0);
  const int g1 = stage_goff(tid + 256, ty0, tx0);
  const int g2 = (tid < SN - 512) ? stage_goff(tid + 512, ty0, tx0) : 0;

  int iob[9]; float cw[9][4];
  bool oob = false;
#pragma unroll
  for (int k = 0; k < 9; ++k) {
    float offy = o2[(e * 27 + 2 * k) * 9216 + p];
    float offx = o2[(e * 27 + 2 * k + 1) * 9216 + p];
    float mk = sigm(o2[(e * 27 + 18 + k) * 9216 + p]);
    float py = (float)(y + k / 3 - 1) + offy;
    float px = (float)(x + k % 3 - 1) + offx;
    float fy = floorf(py), fx = floorf(px);
    float wy = py - fy, wx = px - fx;
    int iy = (int)fy, ix = (int)fx;
#pragma unroll
    for (int dy = 0; dy < 2; ++dy)
#pragma unroll
      for (int dx = 0; dx < 2; ++dx) {
        bool ok = (iy + dy >= 0) && (iy + dy < 96) && (ix + dx >= 0) && (ix + dx < 96);
        cw[k][dy * 2 + dx] =
            (ok ? mk : 0.f) * (dy ? wy : (1.f - wy)) * (dx ? wx : (1.f - wx));
      }
    int ir = iy - (ty0 - 4), ic = ix - (tx0 - 4);
    oob |= ((unsigned)ir > (unsigned)(SH - 2)) | ((unsigned)ic > (unsigned)(SW - 2));
    iob[k] = min(max(ir, 0), SH - 2) * SW + min(max(ic, 0), SW - 2);
  }

  float acc[10];
#pragma unroll
  for (int oc = 0; oc < 10; ++oc) acc[oc] = 0.f;

  float p0 = base[g0], p1 = base[g1], p2 = (tid < SN - 512) ? base[g2] : 0.f;
  for (int c = 0; c < 20; ++c) {
    float* buf = sbuf[c & 1];
    buf[tid] = p0; buf[tid + 256] = p1;
    if (tid < SN - 512) buf[tid + 512] = p2;
    if (c + 1 < 20) {
      const float* ni = base + (c + 1) * 9216;
      p0 = ni[g0]; p1 = ni[g1]; if (tid < SN - 512) p2 = ni[g2];
    }
    __syncthreads();
#pragma unroll
    for (int k = 0; k < 9; ++k) {
      const float* bk = &sbuf[c & 1][iob[k]];
      float sv = cw[k][0] * bk[0] + cw[k][1] * bk[1] +
                 cw[k][2] * bk[SW] + cw[k][3] * bk[SW + 1];
      const float* wc = wm + ((e * 9 + k) * 20 + c) * 10;
#pragma unroll
      for (int oc = 0; oc < 10; ++oc) acc[oc] = fmaf(sv, wc[oc], acc[oc]);
    }
  }

  if (oob) {
#pragma unroll
    for (int oc = 0; oc < 10; ++oc) acc[oc] = 0.f;
    for (int k = 0; k < 9; ++k) {
      float offy = o2[(e * 27 + 2 * k) * 9216 + p];
      float offx = o2[(e * 27 + 2 * k + 1) * 9216 + p];
      float mk = sigm(o2[(e * 27 + 18 + k) * 9216 + p]);
      float py = (float)(y + k / 3 - 1) + offy;
      float px = (float)(x + k % 3 - 1) + offx;
      float fy = floorf(py), fx = floorf(px);
      float wy = py - fy, wx = px - fx;
      int iy = (int)fy, ix = (int)fx;
      int go[4]; float gw[4];
#pragma unroll
      for (int dy = 0; dy < 2; ++dy)
#pragma unroll
        for (int dx = 0; dx < 2; ++dx) {
          bool ok = (iy + dy >= 0) && (iy + dy < 96) && (ix + dx >= 0) && (ix + dx < 96);
          int yc = min(max(iy + dy, 0), 95), xc = min(max(ix + dx, 0), 95);
          go[dy * 2 + dx] = yc * 96 + xc;
          gw[dy * 2 + dx] =
              (ok ? mk : 0.f) * (dy ? wy : (1.f - wy)) * (dx ? wx : (1.f - wx));
        }
      for (int c = 0; c < 20; ++c) {
        const float* ptr = base + c * 9216;
        float sv = gw[0] * ptr[go[0]] + gw[1] * ptr[go[1]] +
                   gw[2] * ptr[go[2]] + gw[3] * ptr[go[3]];
        const float* wc = wm + ((e * 9 + k) * 20 + c) * 10;
#pragma unroll
        for (int oc = 0; oc < 10; ++oc) acc[oc] = fmaf(sv, wc[oc], acc[oc]);
      }
    }
  }
#pragma unroll
  for (int oc = 0; oc < 10; ++oc) {
    float v = s[e * 10 + oc] * acc[oc] + b[e * 10 + oc];
    hout[(e * 10 + oc) * 9216 + p] = fmaxf(v, 0.f);
  }
}

// 1x1 conv p_fea (256ch) -> accfh[j][10][9216], split-K atomic. grid (36,6,4)
__global__ __launch_bounds__(256) void conv_fh_k(
    const float* __restrict__ pfea, const float* __restrict__ wfh,
    float* __restrict__ accfh) {
  const int j = blockIdx.y;
  const int z = blockIdx.z;
  const int p = blockIdx.x * 256 + threadIdx.x;
  const int c_lo = z * 64;
  float acc[10];
#pragma unroll
  for (int c = 0; c < 10; ++c) acc[c] = 0.f;
  for (int ci = c_lo; ci < c_lo + 64; ci += 2) {
    float pv0 = pfea[ci * 9216 + p];
    float pv1 = pfea[(ci + 1) * 9216 + p];
#pragma unroll
    for (int c = 0; c < 10; ++c) {
      acc[c] = fmaf(pv0, wfh[(j * 10 + c) * 256 + ci], acc[c]);
      acc[c] = fmaf(pv1, wfh[(j * 10 + c) * 256 + ci + 1], acc[c]);
    }
  }
#pragma unroll
  for (int c = 0; c < 10; ++c)
    atomicAdd(&accfh[(j * 10 + c) * 9216 + p], acc[c]);
}

// ---------------------------------------------------------------------------
// Node message stage
// ---------------------------------------------------------------------------
__global__ __launch_bounds__(256) void msg_k(
    const float* __restrict__ xp, const float* __restrict__ xh,
    const float* __restrict__ h2, const float* __restrict__ accfh,
    const float* __restrict__ aw, const float* __restrict__ ab,
    const float* __restrict__ bw, const float* __restrict__ bb,
    const float* __restrict__ w1, const float* __restrict__ s1,
    const float* __restrict__ b1, const float* __restrict__ w2,
    const float* __restrict__ b2, const float* __restrict__ sfh,
    const float* __restrict__ bfh, float* __restrict__ msgs) {
  const int j = blockIdx.y;
  const int p = blockIdx.x * 256 + threadIdx.x;
  float xj[10];
#pragma unroll
  for (int c = 0; c < 10; ++c) xj[c] = xp[(j * 10 + c) * 9216 + p];
  float xpp[10];
  int ne = d_ne[j];
  for (int ei = 0; ei < ne; ++ei) {
    int e = d_inc[j][ei];
    int a2 = d_esrc[e];
    float sA = ab[e];
#pragma unroll
    for (int c = 0; c < 10; ++c)
      sA = fmaf(xp[(a2 * 10 + c) * 9216 + p], aw[e * 10 + c], sA);
    float sB = bb[e];
#pragma unroll
    for (int c = 0; c < 10; ++c) sB = fmaf(xj[c], bw[e * 10 + c], sB);
    float f = (1.f - sigm(sA)) * sigm(sB);
#pragma unroll
    for (int c = 0; c < 10; ++c) {
      float mm = f * h2[(e * 10 + c) * 9216 + p];
      xpp[c] = (ei == 0) ? mm : fmaxf(xpp[c], mm);
    }
  }
  const float* hf = xh + ((j < 4) ? 0 : 1) * 10 * 9216;
  float cat[20];
#pragma unroll
  for (int c = 0; c < 10; ++c) cat[c] = hf[c * 9216 + p];
#pragma unroll
  for (int c = 0; c < 10; ++c) cat[10 + c] = xj[c];
  float at = b2[j];
#pragma unroll
  for (int oc = 0; oc < 20; ++oc) {
    float t = 0.f;
#pragma unroll
    for (int c = 0; c < 20; ++c)
      t = fmaf(cat[c], w1[(j * 20 + oc) * 20 + c], t);
    float av = fmaxf(s1[j * 20 + oc] * t + b1[j * 20 + oc], 0.f);
    at = fmaf(av, w2[j * 20 + oc], at);
  }
  at = sigm(at);
#pragma unroll
  for (int c = 0; c < 10; ++c) {
    float xhp = fmaxf(sfh[j * 10 + c] * (at * accfh[(j * 10 + c) * 9216 + p]) +
                          bfh[j * 10 + c], 0.f);
    msgs[(j * 10 + c) * 9216 + p] = xpp[c] + xhp;
  }
}

// ---------------------------------------------------------------------------
// GRU stage. h0 == 0 => gh == bhh constants; z*h term vanishes.
// ---------------------------------------------------------------------------
__global__ __launch_bounds__(256) void gru_k(
    const float* __restrict__ xp, const float* __restrict__ msgs,
    const float* __restrict__ wih1, const float* __restrict__ bih1,
    const float* __restrict__ bhh1, const float* __restrict__ wih2,
    const float* __restrict__ bih2, const float* __restrict__ bhh2,
    float* __restrict__ out) {
  const int j = blockIdx.y;
  const int p = blockIdx.x * 256 + threadIdx.x;
  float xin[20];
#pragma unroll
  for (int c = 0; c < 10; ++c) xin[c] = xp[(j * 10 + c) * 9216 + p];
#pragma unroll
  for (int c = 0; c < 10; ++c) xin[10 + c] = msgs[(j * 10 + c) * 9216 + p];
  float gi[30];
#pragma unroll
  for (int r = 0; r < 30; ++r) gi[r] = bih1[j * 30 + r];
  for (int c = 0; c < 20; ++c) {
    float v = xin[c];
#pragma unroll
    for (int r = 0; r < 30; ++r)
      gi[r] = fmaf(v, wih1[(j * 30 + r) * 20 + c], gi[r]);
  }
  float h1v[10];
#pragma unroll
  for (int c = 0; c < 10; ++c) {
    float r = sigm(gi[c] + bhh1[j * 30 + c]);
    float z = sigm(gi[10 + c] + bhh1[j * 30 + 10 + c]);
    float n = tanhf(gi[20 + c] + r * bhh1[j * 30 + 20 + c]);
    h1v[c] = (1.f - z) * n;
  }
  float g2[30];
#pragma unroll
  for (int r = 0; r < 30; ++r) g2[r] = bih2[j * 30 + r];
  for (int c = 0; c < 10; ++c) {
    float v = h1v[c];
#pragma unroll
    for (int r = 0; r < 30; ++r)
      g2[r] = fmaf(v, wih2[(j * 30 + r) * 10 + c], g2[r]);
  }
#pragma unroll
  for (int c = 0; c < 10; ++c) {
    float r = sigm(g2[c] + bhh2[j * 30 + c]);
    float z = sigm(g2[10 + c] + bhh2[j * 30 + 10 + c]);
    float n = tanhf(g2[20 + c] + r * bhh2[j * 30 + 20 + c]);
    out[(j * 10 + c) * 9216 + p] = (1.f - z) * n;
  }
}

extern "C" void kernel_launch(void* const* d_in, const int* in_sizes, int n_in,
                              void* d_out, int out_size, void* d_ws, size_t ws_size,
                              hipStream_t stream) {
  const float* pfea   = (const float*)d_in[0];
  const float* xp     = (const float*)d_in[1];
  const float* xh     = (const float*)d_in[2];
  const float* dp_ow1 = (const float*)d_in[3];
  const float* dp_ob1 = (const float*)d_in[4];
  const float* dp_w1  = (const float*)d_in[5];
  const float* dp_s1  = (const float*)d_in[6];
  const float* dp_b1  = (const float*)d_in[7];
  const float* dp_ow2 = (const float*)d_in[8];
  const float* dp_ob2 = (const float*)d_in[9];
  const float* dp_w2  = (const float*)d_in[10];
  const float* dp_s2  = (const float*)d_in[11];
  const float* dp_b2  = (const float*)d_in[12];
  const float* dp_aw  = (const float*)d_in[13];
  const float* dp_ab  = (const float*)d_in[14];
  const float* dp_bw  = (const float*)d_in[15];
  const float* dp_bb  = (const float*)d_in[16];
  const float* dc_w1  = (const float*)d_in[17];
  const float* dc_s1  = (const float*)d_in[18];
  const float* dc_b1  = (const float*)d_in[19];
  const float* dc_w2  = (const float*)d_in[20];
  const float* dc_b2  = (const float*)d_in[21];
  const float* dc_wfh = (const float*)d_in[22];
  const float* dc_sfh = (const float*)d_in[23];
  const float* dc_bfh = (const float*)d_in[24];
  const float* g_wih1 = (const float*)d_in[25];
  const float* g_bih1 = (const float*)d_in[26];
  const float* g_bhh1 = (const float*)d_in[28];
  const float* g_wih2 = (const float*)d_in[29];
  const float* g_bih2 = (const float*)d_in[30];
  const float* g_bhh2 = (const float*)d_in[32];

  float* ws  = (float*)d_ws;
  float* wf1 = ws;             // 646380 (dead after offconv1; accfh reuses)
  float* accfh = ws;           //   552960 <= 646380
  float* wf2 = wf1 + 646380;   // 48600
  float* wm1 = wf2 + 48600;    // 478800
  float* wm2 = wm1 + 478800;   // 18000
  float* o1  = wm2 + 18000;    // 2488320 (o2 aliases after dfmain1)
  float* o2  = o1;
  float* h1  = o1 + 2488320;   // 1843200
  float* h2  = h1 + 1843200;   // 921600
  // total ws: 6,444,900 floats = 25.78 MB

  float* out_x = (float*)d_out;        // xp_out: 6*10*9216
  float* out_m = out_x + 552960;       // msgs:   6*10*9216

  prep_w<<<dim3((646380 + 255) / 256), 256, 0, stream>>>(dp_ow1, wf1, 27, 266, 0, 646380);
  prep_w<<<dim3((48600 + 255) / 256), 256, 0, stream>>>(dp_ow2, wf2, 27, 20, 0, 48600);
  prep_w<<<dim3((478800 + 255) / 256), 256, 0, stream>>>(dp_w1, wm1, 20, 266, 1, 478800);
  prep_w<<<dim3((18000 + 255) / 256), 256, 0, stream>>>(dp_w2, wm2, 10, 20, 1, 18000);

  init_o1_k<<<dim3(2488320 / 256), 256, 0, stream>>>(dp_ob1, o1);
  hipMemsetAsync(h1, 0, 1843200 * sizeof(float), stream);

  dim3 blk(256);
  offconv1_k<<<dim3(10, 36, 4), blk, 0, stream>>>(pfea, xp, wf1, o1);
  dfmain1_k<<<dim3(10, 36, 4), blk, 0, stream>>>(pfea, xp, o1, wm1, h1);
  fin_h1_k<<<dim3(1843200 / 256), blk, 0, stream>>>(h1, dp_s1, dp_b1);

  offconv2_k<<<dim3(10, 36), blk, 0, stream>>>(h1, wf2, dp_ob2, o2);
  dfmain2_k<<<dim3(10, 36), blk, 0, stream>>>(h1, o2, wm2, dp_s2, dp_b2, h2);

  hipMemsetAsync(accfh, 0, 552960 * sizeof(float), stream);
  conv_fh_k<<<dim3(36, 6, 4), blk, 0, stream>>>(pfea, dc_wfh, accfh);

  msg_k<<<dim3(36, 6), blk, 0, stream>>>(xp, xh, h2, accfh,
                                         dp_aw, dp_ab, dp_bw, dp_bb,
                                         dc_w1, dc_s1, dc_b1, dc_w2, dc_b2,
                                         dc_sfh, dc_bfh, out_m);
  gru_k<<<dim3(36, 6), blk, 0, stream>>>(xp, out_m, g_wih1, g_bih1, g_bhh1,
                                         g_wih2, g_bih2, g_bhh2, out_x);
}

// Round 5
// 716.136 us; speedup vs baseline: 2.7116x; 1.0748x over previous
//
#include <hip/hip_runtime.h>
#include <hip/hip_bf16.h>

#define DEV static __device__ __forceinline__

DEV float sigm(float x) { return 1.f / (1.f + __expf(-x)); }

// Edge tables from ADJ nonzeros: (src, dst) pairs in np.nonzero order
__constant__ int d_esrc[10] = {0,1,1,1,2,2,3,4,4,5};
__constant__ int d_inc[6][3] = {{1,-1,-1},{0,4,7},{2,6,-1},{5,-1,-1},{3,9,-1},{8,-1,-1}};
__constant__ int d_ne[6] = {1,3,2,1,2,1};

// Tile geometry: 32x8 px per block, halo 4 -> 16 rows x 40 data cols,
// row stride padded to 41 (odd) to break LDS bank aliasing.
#define TW 32
#define TH 8
#define SW 41      // padded stride
#define SDC 40     // data cols
#define SH 16
#define SN 656     // SH*SW

// ---------------------------------------------------------------------------
// Weight prep (transpose for block-uniform scalar loads).
//   src: [e][OC][C][3][3]
//   dst: tap_major=0: [e][C][9][OC]   tap_major=1: [e][9][C][OC]
// ---------------------------------------------------------------------------
__global__ void prep_w(const float* __restrict__ src, float* __restrict__ dst,
                       int OC, int C, int tap_major, int total) {
  int i = blockIdx.x * 256 + threadIdx.x;
  if (i >= total) return;
  int t = i % 9; int n = i / 9;
  int c = n % C; n /= C;
  int oc = n % OC; int e = n / OC;
  float v = src[i];
  int inner = tap_major ? (t * C + c) : (c * 9 + t);
  dst[(e * C * 9 + inner) * OC + oc] = v;
}

// o1 = bias broadcast; h1a = 0.  total = 2488320 + 1843200
__global__ void init_k(const float* __restrict__ ob, float* __restrict__ o1,
                       float* __restrict__ h1a) {
  int i = blockIdx.x * 256 + threadIdx.x;
  if (i < 2488320) o1[i] = ob[i / 9216];
  else h1a[i - 2488320] = 0.f;
}

// Staging address: element i of padded 16x41 window (col 40 duplicates 39).
DEV int stage_goff(int i, int ty0, int tx0) {
  int r = i / SW, cl = i % SW;
  cl = min(cl, SDC - 1);
  int gy = min(max(ty0 - 4 + r, 0), 95);
  int gx = min(max(tx0 - 4 + cl, 0), 95);
  return gy * 96 + gx;
}

// ---------------------------------------------------------------------------
// Offset conv 1 (3x3 SAME, LDS-tiled, pair-staged, split-K z=8, atomic).
// grid (10, 36, 8)
// ---------------------------------------------------------------------------
__global__ __launch_bounds__(256) void offconv1_k(
    const float* __restrict__ pfea, const float* __restrict__ xp,
    const float* __restrict__ wf, float* __restrict__ o1) {
  __shared__ float sbuf[2][2 * SN];
  const int e = blockIdx.x, m = blockIdx.y, z = blockIdx.z;
  const int tid = threadIdx.x;
  const int tx = tid % TW, ty = tid / TW;
  const int tx0 = (m % 3) * TW, ty0 = (m / 3) * TH;
  const int y = ty0 + ty, x = tx0 + tx;
  const int p = y * 96 + x;
  const float* xpe = xp + d_esrc[e] * 10 * 9216;
  const int c_lo = (z * 266) / 8, c_hi = ((z + 1) * 266) / 8;

  const int g0 = stage_goff(tid, ty0, tx0);
  const int g1 = stage_goff(tid + 256, ty0, tx0);
  const int g2 = (tid < SN - 512) ? stage_goff(tid + 512, ty0, tx0) : 0;

  float vmask[9];
#pragma unroll
  for (int t = 0; t < 9; ++t) {
    int yy = y + t / 3 - 1, xx = x + t % 3 - 1;
    vmask[t] = ((yy >= 0) && (yy < 96) && (xx >= 0) && (xx < 96)) ? 1.f : 0.f;
  }
  const int vbase = (ty + 3) * SW + (tx + 3);

  float acc[27];
#pragma unroll
  for (int oc = 0; oc < 27; ++oc) acc[oc] = 0.f;

#define IMG1(c) (((c) < 256) ? (pfea + (c) * 9216) : (xpe + ((c) - 256) * 9216))
  const float* ia = IMG1(c_lo);
  const float* ib = IMG1(min(c_lo + 1, c_hi - 1));
  float pa0 = ia[g0], pa1 = ia[g1], pa2 = (tid < SN - 512) ? ia[g2] : 0.f;
  float pb0 = ib[g0], pb1 = ib[g1], pb2 = (tid < SN - 512) ? ib[g2] : 0.f;

  int bsel = 0;
  for (int c = c_lo; c < c_hi; c += 2, bsel ^= 1) {
    float* buf = sbuf[bsel];
    buf[tid] = pa0; buf[tid + 256] = pa1;
    if (tid < SN - 512) buf[tid + 512] = pa2;
    buf[SN + tid] = pb0; buf[SN + tid + 256] = pb1;
    if (tid < SN - 512) buf[SN + tid + 512] = pb2;
    if (c + 2 < c_hi) {
      const float* na = IMG1(c + 2);
      const float* nb = IMG1(min(c + 3, c_hi - 1));
      pa0 = na[g0]; pa1 = na[g1]; if (tid < SN - 512) pa2 = na[g2];
      pb0 = nb[g0]; pb1 = nb[g1]; if (tid < SN - 512) pb2 = nb[g2];
    }
    __syncthreads();
    {
      const float* wc = wf + (e * 266 + c) * 243;
#pragma unroll
      for (int t = 0; t < 9; ++t) {
        float v = vmask[t] * buf[vbase + (t / 3) * SW + (t % 3)];
#pragma unroll
        for (int oc = 0; oc < 27; ++oc)
          acc[oc] = fmaf(v, wc[t * 27 + oc], acc[oc]);
      }
    }
    if (c + 1 < c_hi) {
      const float* wc = wf + (e * 266 + c + 1) * 243;
      const float* b2p = buf + SN;
#pragma unroll
      for (int t = 0; t < 9; ++t) {
        float v = vmask[t] * b2p[vbase + (t / 3) * SW + (t % 3)];
#pragma unroll
        for (int oc = 0; oc < 27; ++oc)
          acc[oc] = fmaf(v, wc[t * 27 + oc], acc[oc]);
      }
    }
  }
#pragma unroll
  for (int oc = 0; oc < 27; ++oc)
    atomicAdd(&o1[(e * 27 + oc) * 9216 + p], acc[oc]);
}

// ---------------------------------------------------------------------------
// Deformable main conv 1 (LDS bilinear, pair-staged, split-K z=8, atomic).
// grid (10, 36, 8)
// ---------------------------------------------------------------------------
__global__ __launch_bounds__(256) void dfmain1_k(
    const float* __restrict__ pfea, const float* __restrict__ xp,
    const float* __restrict__ o1, const float* __restrict__ wm,
    float* __restrict__ hacc) {
  __shared__ float sbuf[2][2 * SN];
  const int e = blockIdx.x, m = blockIdx.y, z = blockIdx.z;
  const int tid = threadIdx.x;
  const int tx = tid % TW, ty = tid / TW;
  const int tx0 = (m % 3) * TW, ty0 = (m / 3) * TH;
  const int y = ty0 + ty, x = tx0 + tx;
  const int p = y * 96 + x;
  const float* xpe = xp + d_esrc[e] * 10 * 9216;
  const int c_lo = (z * 266) / 8, c_hi = ((z + 1) * 266) / 8;

  const int g0 = stage_goff(tid, ty0, tx0);
  const int g1 = stage_goff(tid + 256, ty0, tx0);
  const int g2 = (tid < SN - 512) ? stage_goff(tid + 512, ty0, tx0) : 0;

  int iob[9]; float cw[9][4];
  bool oob = false;
#pragma unroll
  for (int k = 0; k < 9; ++k) {
    float offy = o1[(e * 27 + 2 * k) * 9216 + p];
    float offx = o1[(e * 27 + 2 * k + 1) * 9216 + p];
    float mk = sigm(o1[(e * 27 + 18 + k) * 9216 + p]);
    float py = (float)(y + k / 3 - 1) + offy;
    float px = (float)(x + k % 3 - 1) + offx;
    float fy = floorf(py), fx = floorf(px);
    float wy = py - fy, wx = px - fx;
    int iy = (int)fy, ix = (int)fx;
#pragma unroll
    for (int dy = 0; dy < 2; ++dy)
#pragma unroll
      for (int dx = 0; dx < 2; ++dx) {
        bool ok = (iy + dy >= 0) && (iy + dy < 96) && (ix + dx >= 0) && (ix + dx < 96);
        cw[k][dy * 2 + dx] =
            (ok ? mk : 0.f) * (dy ? wy : (1.f - wy)) * (dx ? wx : (1.f - wx));
      }
    int ir = iy - (ty0 - 4), ic = ix - (tx0 - 4);
    oob |= ((unsigned)ir > (unsigned)(SH - 2)) | ((unsigned)ic > (unsigned)(SDC - 2));
    iob[k] = min(max(ir, 0), SH - 2) * SW + min(max(ic, 0), SDC - 2);
  }

  float acc[20];
#pragma unroll
  for (int oc = 0; oc < 20; ++oc) acc[oc] = 0.f;

  const float* ia = IMG1(c_lo);
  const float* ib = IMG1(min(c_lo + 1, c_hi - 1));
  float pa0 = ia[g0], pa1 = ia[g1], pa2 = (tid < SN - 512) ? ia[g2] : 0.f;
  float pb0 = ib[g0], pb1 = ib[g1], pb2 = (tid < SN - 512) ? ib[g2] : 0.f;

  int bsel = 0;
  for (int c = c_lo; c < c_hi; c += 2, bsel ^= 1) {
    float* buf = sbuf[bsel];
    buf[tid] = pa0; buf[tid + 256] = pa1;
    if (tid < SN - 512) buf[tid + 512] = pa2;
    buf[SN + tid] = pb0; buf[SN + tid + 256] = pb1;
    if (tid < SN - 512) buf[SN + tid + 512] = pb2;
    if (c + 2 < c_hi) {
      const float* na = IMG1(c + 2);
      const float* nb = IMG1(min(c + 3, c_hi - 1));
      pa0 = na[g0]; pa1 = na[g1]; if (tid < SN - 512) pa2 = na[g2];
      pb0 = nb[g0]; pb1 = nb[g1]; if (tid < SN - 512) pb2 = nb[g2];
    }
    __syncthreads();
    {
#pragma unroll
      for (int k = 0; k < 9; ++k) {
        const float* bk = buf + iob[k];
        float sv = cw[k][0] * bk[0] + cw[k][1] * bk[1] +
                   cw[k][2] * bk[SW] + cw[k][3] * bk[SW + 1];
        const float* wc = wm + ((e * 9 + k) * 266 + c) * 20;
#pragma unroll
        for (int oc = 0; oc < 20; ++oc) acc[oc] = fmaf(sv, wc[oc], acc[oc]);
      }
    }
    if (c + 1 < c_hi) {
      const float* bufb = buf + SN;
#pragma unroll
      for (int k = 0; k < 9; ++k) {
        const float* bk = bufb + iob[k];
        float sv = cw[k][0] * bk[0] + cw[k][1] * bk[1] +
                   cw[k][2] * bk[SW] + cw[k][3] * bk[SW + 1];
        const float* wc = wm + ((e * 9 + k) * 266 + c + 1) * 20;
#pragma unroll
        for (int oc = 0; oc < 20; ++oc) acc[oc] = fmaf(sv, wc[oc], acc[oc]);
      }
    }
  }

  // Per-lane slow path: offsets escaped the halo.
  if (oob) {
#pragma unroll
    for (int oc = 0; oc < 20; ++oc) acc[oc] = 0.f;
    for (int k = 0; k < 9; ++k) {
      float offy = o1[(e * 27 + 2 * k) * 9216 + p];
      float offx = o1[(e * 27 + 2 * k + 1) * 9216 + p];
      float mk = sigm(o1[(e * 27 + 18 + k) * 9216 + p]);
      float py = (float)(y + k / 3 - 1) + offy;
      float px = (float)(x + k % 3 - 1) + offx;
      float fy = floorf(py), fx = floorf(px);
      float wy = py - fy, wx = px - fx;
      int iy = (int)fy, ix = (int)fx;
      int go[4]; float gw[4];
#pragma unroll
      for (int dy = 0; dy < 2; ++dy)
#pragma unroll
        for (int dx = 0; dx < 2; ++dx) {
          bool ok = (iy + dy >= 0) && (iy + dy < 96) && (ix + dx >= 0) && (ix + dx < 96);
          int yc = min(max(iy + dy, 0), 95), xc = min(max(ix + dx, 0), 95);
          go[dy * 2 + dx] = yc * 96 + xc;
          gw[dy * 2 + dx] =
              (ok ? mk : 0.f) * (dy ? wy : (1.f - wy)) * (dx ? wx : (1.f - wx));
        }
      for (int c = c_lo; c < c_hi; ++c) {
        const float* ptr = IMG1(c);
        float sv = gw[0] * ptr[go[0]] + gw[1] * ptr[go[1]] +
                   gw[2] * ptr[go[2]] + gw[3] * ptr[go[3]];
        const float* wc = wm + ((e * 9 + k) * 266 + c) * 20;
#pragma unroll
        for (int oc = 0; oc < 20; ++oc) acc[oc] = fmaf(sv, wc[oc], acc[oc]);
      }
    }
  }
#pragma unroll
  for (int oc = 0; oc < 20; ++oc)
    atomicAdd(&hacc[(e * 20 + oc) * 9216 + p], acc[oc]);
}

// ---------------------------------------------------------------------------
// Offset conv 2: 3x3 SAME on h1 = relu(s1*h1a+b1) applied at staging.
// grid (10, 36)
// ---------------------------------------------------------------------------
__global__ __launch_bounds__(256) void offconv2_k(
    const float* __restrict__ h1a, const float* __restrict__ wf,
    const float* __restrict__ ob, const float* __restrict__ s1,
    const float* __restrict__ b1, float* __restrict__ o2) {
  __shared__ float sbuf[2][2 * SN];
  const int e = blockIdx.x, m = blockIdx.y;
  const int tid = threadIdx.x;
  const int tx = tid % TW, ty = tid / TW;
  const int tx0 = (m % 3) * TW, ty0 = (m / 3) * TH;
  const int y = ty0 + ty, x = tx0 + tx;
  const int p = y * 96 + x;
  const float* base = h1a + e * 20 * 9216;

  const int g0 = stage_goff(tid, ty0, tx0);
  const int g1 = stage_goff(tid + 256, ty0, tx0);
  const int g2 = (tid < SN - 512) ? stage_goff(tid + 512, ty0, tx0) : 0;

  float vmask[9];
#pragma unroll
  for (int t = 0; t < 9; ++t) {
    int yy = y + t / 3 - 1, xx = x + t % 3 - 1;
    vmask[t] = ((yy >= 0) && (yy < 96) && (xx >= 0) && (xx < 96)) ? 1.f : 0.f;
  }
  const int vbase = (ty + 3) * SW + (tx + 3);

  float acc[27];
#pragma unroll
  for (int oc = 0; oc < 27; ++oc) acc[oc] = ob[e * 27 + oc];

  const float* ia = base;
  const float* ib = base + 9216;
  float pa0 = ia[g0], pa1 = ia[g1], pa2 = (tid < SN - 512) ? ia[g2] : 0.f;
  float pb0 = ib[g0], pb1 = ib[g1], pb2 = (tid < SN - 512) ? ib[g2] : 0.f;

  int bsel = 0;
  for (int c = 0; c < 20; c += 2, bsel ^= 1) {
    float sa = s1[e * 20 + c], ba = b1[e * 20 + c];
    float sb = s1[e * 20 + c + 1], bb2 = b1[e * 20 + c + 1];
    float* buf = sbuf[bsel];
    buf[tid] = fmaxf(fmaf(sa, pa0, ba), 0.f);
    buf[tid + 256] = fmaxf(fmaf(sa, pa1, ba), 0.f);
    if (tid < SN - 512) buf[tid + 512] = fmaxf(fmaf(sa, pa2, ba), 0.f);
    buf[SN + tid] = fmaxf(fmaf(sb, pb0, bb2), 0.f);
    buf[SN + tid + 256] = fmaxf(fmaf(sb, pb1, bb2), 0.f);
    if (tid < SN - 512) buf[SN + tid + 512] = fmaxf(fmaf(sb, pb2, bb2), 0.f);
    if (c + 2 < 20) {
      const float* na = base + (c + 2) * 9216;
      const float* nb = base + (c + 3) * 9216;
      pa0 = na[g0]; pa1 = na[g1]; if (tid < SN - 512) pa2 = na[g2];
      pb0 = nb[g0]; pb1 = nb[g1]; if (tid < SN - 512) pb2 = nb[g2];
    }
    __syncthreads();
#pragma unroll
    for (int cc = 0; cc < 2; ++cc) {
      const float* wc = wf + (e * 20 + c + cc) * 243;
      const float* bp = buf + cc * SN;
#pragma unroll
      for (int t = 0; t < 9; ++t) {
        float v = vmask[t] * bp[vbase + (t / 3) * SW + (t % 3)];
#pragma unroll
        for (int oc = 0; oc < 27; ++oc)
          acc[oc] = fmaf(v, wc[t * 27 + oc], acc[oc]);
      }
    }
  }
#pragma unroll
  for (int oc = 0; oc < 27; ++oc) o2[(e * 27 + oc) * 9216 + p] = acc[oc];
}

// ---------------------------------------------------------------------------
// Deformable main conv 2: h1 affine+relu at staging; epilogue s2/b2+relu.
// grid (10, 36)
// ---------------------------------------------------------------------------
__global__ __launch_bounds__(256) void dfmain2_k(
    const float* __restrict__ h1a, const float* __restrict__ o2,
    const float* __restrict__ wm, const float* __restrict__ s1,
    const float* __restrict__ b1, const float* __restrict__ s2,
    const float* __restrict__ b2, float* __restrict__ hout) {
  __shared__ float sbuf[2][2 * SN];
  const int e = blockIdx.x, m = blockIdx.y;
  const int tid = threadIdx.x;
  const int tx = tid % TW, ty = tid / TW;
  const int tx0 = (m % 3) * TW, ty0 = (m / 3) * TH;
  const int y = ty0 + ty, x = tx0 + tx;
  const int p = y * 96 + x;
  const float* base = h1a + e * 20 * 9216;

  const int g0 = stage_goff(tid, ty0, tx0);
  const int g1 = stage_goff(tid + 256, ty0, tx0);
  const int g2 = (tid < SN - 512) ? stage_goff(tid + 512, ty0, tx0) : 0;

  int iob[9]; float cw[9][4];
  bool oob = false;
#pragma unroll
  for (int k = 0; k < 9; ++k) {
    float offy = o2[(e * 27 + 2 * k) * 9216 + p];
    float offx = o2[(e * 27 + 2 * k + 1) * 9216 + p];
    float mk = sigm(o2[(e * 27 + 18 + k) * 9216 + p]);
    float py = (float)(y + k / 3 - 1) + offy;
    float px = (float)(x + k % 3 - 1) + offx;
    float fy = floorf(py), fx = floorf(px);
    float wy = py - fy, wx = px - fx;
    int iy = (int)fy, ix = (int)fx;
#pragma unroll
    for (int dy = 0; dy < 2; ++dy)
#pragma unroll
      for (int dx = 0; dx < 2; ++dx) {
        bool ok = (iy + dy >= 0) && (iy + dy < 96) && (ix + dx >= 0) && (ix + dx < 96);
        cw[k][dy * 2 + dx] =
            (ok ? mk : 0.f) * (dy ? wy : (1.f - wy)) * (dx ? wx : (1.f - wx));
      }
    int ir = iy - (ty0 - 4), ic = ix - (tx0 - 4);
    oob |= ((unsigned)ir > (unsigned)(SH - 2)) | ((unsigned)ic > (unsigned)(SDC - 2));
    iob[k] = min(max(ir, 0), SH - 2) * SW + min(max(ic, 0), SDC - 2);
  }

  float acc[10];
#pragma unroll
  for (int oc = 0; oc < 10; ++oc) acc[oc] = 0.f;

  const float* ia = base;
  const float* ib = base + 9216;
  float pa0 = ia[g0], pa1 = ia[g1], pa2 = (tid < SN - 512) ? ia[g2] : 0.f;
  float pb0 = ib[g0], pb1 = ib[g1], pb2 = (tid < SN - 512) ? ib[g2] : 0.f;

  int bsel = 0;
  for (int c = 0; c < 20; c += 2, bsel ^= 1) {
    float sa = s1[e * 20 + c], ba = b1[e * 20 + c];
    float sb = s1[e * 20 + c + 1], bb2 = b1[e * 20 + c + 1];
    float* buf = sbuf[bsel];
    buf[tid] = fmaxf(fmaf(sa, pa0, ba), 0.f);
    buf[tid + 256] = fmaxf(fmaf(sa, pa1, ba), 0.f);
    if (tid < SN - 512) buf[tid + 512] = fmaxf(fmaf(sa, pa2, ba), 0.f);
    buf[SN + tid] = fmaxf(fmaf(sb, pb0, bb2), 0.f);
    buf[SN + tid + 256] = fmaxf(fmaf(sb, pb1, bb2), 0.f);
    if (tid < SN - 512) buf[SN + tid + 512] = fmaxf(fmaf(sb, pb2, bb2), 0.f);
    if (c + 2 < 20) {
      const float* na = base + (c + 2) * 9216;
      const float* nb = base + (c + 3) * 9216;
      pa0 = na[g0]; pa1 = na[g1]; if (tid < SN - 512) pa2 = na[g2];
      pb0 = nb[g0]; pb1 = nb[g1]; if (tid < SN - 512) pb2 = nb[g2];
    }
    __syncthreads();
#pragma unroll
    for (int cc = 0; cc < 2; ++cc) {
      const float* bp = buf + cc * SN;
#pragma unroll
      for (int k = 0; k < 9; ++k) {
        const float* bk = bp + iob[k];
        float sv = cw[k][0] * bk[0] + cw[k][1] * bk[1] +
                   cw[k][2] * bk[SW] + cw[k][3] * bk[SW + 1];
        const float* wc = wm + ((e * 9 + k) * 20 + c + cc) * 10;
#pragma unroll
        for (int oc = 0; oc < 10; ++oc) acc[oc] = fmaf(sv, wc[oc], acc[oc]);
      }
    }
  }

  if (oob) {
#pragma unroll
    for (int oc = 0; oc < 10; ++oc) acc[oc] = 0.f;
    for (int k = 0; k < 9; ++k) {
      float offy = o2[(e * 27 + 2 * k) * 9216 + p];
      float offx = o2[(e * 27 + 2 * k + 1) * 9216 + p];
      float mk = sigm(o2[(e * 27 + 18 + k) * 9216 + p]);
      float py = (float)(y + k / 3 - 1) + offy;
      float px = (float)(x + k % 3 - 1) + offx;
      float fy = floorf(py), fx = floorf(px);
      float wy = py - fy, wx = px - fx;
      int iy = (int)fy, ix = (int)fx;
      int go[4]; float gw[4];
#pragma unroll
      for (int dy = 0; dy < 2; ++dy)
#pragma unroll
        for (int dx = 0; dx < 2; ++dx) {
          bool ok = (iy + dy >= 0) && (iy + dy < 96) && (ix + dx >= 0) && (ix + dx < 96);
          int yc = min(max(iy + dy, 0), 95), xc = min(max(ix + dx, 0), 95);
          go[dy * 2 + dx] = yc * 96 + xc;
          gw[dy * 2 + dx] =
              (ok ? mk : 0.f) * (dy ? wy : (1.f - wy)) * (dx ? wx : (1.f - wx));
        }
      for (int c = 0; c < 20; ++c) {
        float sc = s1[e * 20 + c], bc = b1[e * 20 + c];
        const float* ptr = base + c * 9216;
        float v0 = fmaxf(fmaf(sc, ptr[go[0]], bc), 0.f);
        float v1 = fmaxf(fmaf(sc, ptr[go[1]], bc), 0.f);
        float v2 = fmaxf(fmaf(sc, ptr[go[2]], bc), 0.f);
        float v3 = fmaxf(fmaf(sc, ptr[go[3]], bc), 0.f);
        float sv = gw[0] * v0 + gw[1] * v1 + gw[2] * v2 + gw[3] * v3;
        const float* wc = wm + ((e * 9 + k) * 20 + c) * 10;
#pragma unroll
        for (int oc = 0; oc < 10; ++oc) acc[oc] = fmaf(sv, wc[oc], acc[oc]);
      }
    }
  }
#pragma unroll
  for (int oc = 0; oc < 10; ++oc) {
    float v = s2[e * 10 + oc] * acc[oc] + b2[e * 10 + oc];
    hout[(e * 10 + oc) * 9216 + p] = fmaxf(v, 0.f);
  }
}

// 1x1 conv p_fea (256ch) -> accfh[j][10][9216], split-K atomic. grid (36,6,4)
__global__ __launch_bounds__(256) void conv_fh_k(
    const float* __restrict__ pfea, const float* __restrict__ wfh,
    float* __restrict__ accfh) {
  const int j = blockIdx.y;
  const int z = blockIdx.z;
  const int p = blockIdx.x * 256 + threadIdx.x;
  const int c_lo = z * 64;
  float acc[10];
#pragma unroll
  for (int c = 0; c < 10; ++c) acc[c] = 0.f;
  for (int ci = c_lo; ci < c_lo + 64; ci += 4) {
    float pv0 = pfea[ci * 9216 + p];
    float pv1 = pfea[(ci + 1) * 9216 + p];
    float pv2 = pfea[(ci + 2) * 9216 + p];
    float pv3 = pfea[(ci + 3) * 9216 + p];
#pragma unroll
    for (int c = 0; c < 10; ++c) {
      acc[c] = fmaf(pv0, wfh[(j * 10 + c) * 256 + ci], acc[c]);
      acc[c] = fmaf(pv1, wfh[(j * 10 + c) * 256 + ci + 1], acc[c]);
      acc[c] = fmaf(pv2, wfh[(j * 10 + c) * 256 + ci + 2], acc[c]);
      acc[c] = fmaf(pv3, wfh[(j * 10 + c) * 256 + ci + 3], acc[c]);
    }
  }
#pragma unroll
  for (int c = 0; c < 10; ++c)
    atomicAdd(&accfh[(j * 10 + c) * 9216 + p], acc[c]);
}

// ---------------------------------------------------------------------------
// Fused node-message + GRU stage. h0==0 => gh==bhh; z*h term vanishes.
// grid (36, 6)
// ---------------------------------------------------------------------------
__global__ __launch_bounds__(256) void msggru_k(
    const float* __restrict__ xp, const float* __restrict__ xh,
    const float* __restrict__ h2, const float* __restrict__ accfh,
    const float* __restrict__ aw, const float* __restrict__ ab,
    const float* __restrict__ bw, const float* __restrict__ bb,
    const float* __restrict__ w1, const float* __restrict__ s1,
    const float* __restrict__ b1, const float* __restrict__ w2,
    const float* __restrict__ b2, const float* __restrict__ sfh,
    const float* __restrict__ bfh,
    const float* __restrict__ wih1, const float* __restrict__ bih1,
    const float* __restrict__ bhh1, const float* __restrict__ wih2,
    const float* __restrict__ bih2, const float* __restrict__ bhh2,
    float* __restrict__ out_m, float* __restrict__ out_x) {
  const int j = blockIdx.y;
  const int p = blockIdx.x * 256 + threadIdx.x;
  float xj[10];
#pragma unroll
  for (int c = 0; c < 10; ++c) xj[c] = xp[(j * 10 + c) * 9216 + p];
  float xpp[10];
  int ne = d_ne[j];
  for (int ei = 0; ei < ne; ++ei) {
    int e = d_inc[j][ei];
    int a2 = d_esrc[e];
    float sA = ab[e];
#pragma unroll
    for (int c = 0; c < 10; ++c)
      sA = fmaf(xp[(a2 * 10 + c) * 9216 + p], aw[e * 10 + c], sA);
    float sB = bb[e];
#pragma unroll
    for (int c = 0; c < 10; ++c) sB = fmaf(xj[c], bw[e * 10 + c], sB);
    float f = (1.f - sigm(sA)) * sigm(sB);
#pragma unroll
    for (int c = 0; c < 10; ++c) {
      float mm = f * h2[(e * 10 + c) * 9216 + p];
      xpp[c] = (ei == 0) ? mm : fmaxf(xpp[c], mm);
    }
  }
  const float* hf = xh + ((j < 4) ? 0 : 1) * 10 * 9216;
  float cat[20];
#pragma unroll
  for (int c = 0; c < 10; ++c) cat[c] = hf[c * 9216 + p];
#pragma unroll
  for (int c = 0; c < 10; ++c) cat[10 + c] = xj[c];
  float at = b2[j];
#pragma unroll
  for (int oc = 0; oc < 20; ++oc) {
    float t = 0.f;
#pragma unroll
    for (int c = 0; c < 20; ++c)
      t = fmaf(cat[c], w1[(j * 20 + oc) * 20 + c], t);
    float av = fmaxf(s1[j * 20 + oc] * t + b1[j * 20 + oc], 0.f);
    at = fmaf(av, w2[j * 20 + oc], at);
  }
  at = sigm(at);
  float msg[10];
#pragma unroll
  for (int c = 0; c < 10; ++c) {
    float xhp = fmaxf(sfh[j * 10 + c] * (at * accfh[(j * 10 + c) * 9216 + p]) +
                          bfh[j * 10 + c], 0.f);
    msg[c] = xpp[c] + xhp;
    out_m[(j * 10 + c) * 9216 + p] = msg[c];
  }
  // GRU (two cells, h0 = 0)
  float gi[30];
#pragma unroll
  for (int r = 0; r < 30; ++r) gi[r] = bih1[j * 30 + r];
#pragma unroll
  for (int c = 0; c < 10; ++c) {
    float v = xj[c];
#pragma unroll
    for (int r = 0; r < 30; ++r)
      gi[r] = fmaf(v, wih1[(j * 30 + r) * 20 + c], gi[r]);
  }
#pragma unroll
  for (int c = 0; c < 10; ++c) {
    float v = msg[c];
#pragma unroll
    for (int r = 0; r < 30; ++r)
      gi[r] = fmaf(v, wih1[(j * 30 + r) * 20 + 10 + c], gi[r]);
  }
  float h1v[10];
#pragma unroll
  for (int c = 0; c < 10; ++c) {
    float r = sigm(gi[c] + bhh1[j * 30 + c]);
    float z = sigm(gi[10 + c] + bhh1[j * 30 + 10 + c]);
    float n = tanhf(gi[20 + c] + r * bhh1[j * 30 + 20 + c]);
    h1v[c] = (1.f - z) * n;
  }
  float g2v[30];
#pragma unroll
  for (int r = 0; r < 30; ++r) g2v[r] = bih2[j * 30 + r];
#pragma unroll
  for (int c = 0; c < 10; ++c) {
    float v = h1v[c];
#pragma unroll
    for (int r = 0; r < 30; ++r)
      g2v[r] = fmaf(v, wih2[(j * 30 + r) * 10 + c], g2v[r]);
  }
#pragma unroll
  for (int c = 0; c < 10; ++c) {
    float r = sigm(g2v[c] + bhh2[j * 30 + c]);
    float z = sigm(g2v[10 + c] + bhh2[j * 30 + 10 + c]);
    float n = tanhf(g2v[20 + c] + r * bhh2[j * 30 + 20 + c]);
    out_x[(j * 10 + c) * 9216 + p] = (1.f - z) * n;
  }
}

extern "C" void kernel_launch(void* const* d_in, const int* in_sizes, int n_in,
                              void* d_out, int out_size, void* d_ws, size_t ws_size,
                              hipStream_t stream) {
  const float* pfea   = (const float*)d_in[0];
  const float* xp     = (const float*)d_in[1];
  const float* xh     = (const float*)d_in[2];
  const float* dp_ow1 = (const float*)d_in[3];
  const float* dp_ob1 = (const float*)d_in[4];
  const float* dp_w1  = (const float*)d_in[5];
  const float* dp_s1  = (const float*)d_in[6];
  const float* dp_b1  = (const float*)d_in[7];
  const float* dp_ow2 = (const float*)d_in[8];
  const float* dp_ob2 = (const float*)d_in[9];
  const float* dp_w2  = (const float*)d_in[10];
  const float* dp_s2  = (const float*)d_in[11];
  const float* dp_b2  = (const float*)d_in[12];
  const float* dp_aw  = (const float*)d_in[13];
  const float* dp_ab  = (const float*)d_in[14];
  const float* dp_bw  = (const float*)d_in[15];
  const float* dp_bb  = (const float*)d_in[16];
  const float* dc_w1  = (const float*)d_in[17];
  const float* dc_s1  = (const float*)d_in[18];
  const float* dc_b1  = (const float*)d_in[19];
  const float* dc_w2  = (const float*)d_in[20];
  const float* dc_b2  = (const float*)d_in[21];
  const float* dc_wfh = (const float*)d_in[22];
  const float* dc_sfh = (const float*)d_in[23];
  const float* dc_bfh = (const float*)d_in[24];
  const float* g_wih1 = (const float*)d_in[25];
  const float* g_bih1 = (const float*)d_in[26];
  const float* g_bhh1 = (const float*)d_in[28];
  const float* g_wih2 = (const float*)d_in[29];
  const float* g_bih2 = (const float*)d_in[30];
  const float* g_bhh2 = (const float*)d_in[32];

  float* ws  = (float*)d_ws;
  float* wf1 = ws;             // 646380 (dead after offconv1; accfh reuses)
  float* accfh = ws;           //   552960 <= 646380
  float* wf2 = wf1 + 646380;   // 48600
  float* wm1 = wf2 + 48600;    // 478800
  float* wm2 = wm1 + 478800;   // 18000
  float* o1  = wm2 + 18000;    // 2488320 (o2 aliases after dfmain1)
  float* o2  = o1;
  float* h1a = o1 + 2488320;   // 1843200 (raw accumulator; affine at use)
  float* h2  = h1a + 1843200;  // 921600
  // total ws: 6,444,900 floats = 25.78 MB

  float* out_x = (float*)d_out;        // xp_out: 6*10*9216
  float* out_m = out_x + 552960;       // msgs:   6*10*9216

  prep_w<<<dim3((646380 + 255) / 256), 256, 0, stream>>>(dp_ow1, wf1, 27, 266, 0, 646380);
  prep_w<<<dim3((48600 + 255) / 256), 256, 0, stream>>>(dp_ow2, wf2, 27, 20, 0, 48600);
  prep_w<<<dim3((478800 + 255) / 256), 256, 0, stream>>>(dp_w1, wm1, 20, 266, 1, 478800);
  prep_w<<<dim3((18000 + 255) / 256), 256, 0, stream>>>(dp_w2, wm2, 10, 20, 1, 18000);

  init_k<<<dim3(16920), 256, 0, stream>>>(dp_ob1, o1, h1a);

  dim3 blk(256);
  offconv1_k<<<dim3(10, 36, 8), blk, 0, stream>>>(pfea, xp, wf1, o1);
  dfmain1_k<<<dim3(10, 36, 8), blk, 0, stream>>>(pfea, xp, o1, wm1, h1a);

  offconv2_k<<<dim3(10, 36), blk, 0, stream>>>(h1a, wf2, dp_ob2, dp_s1, dp_b1, o2);
  dfmain2_k<<<dim3(10, 36), blk, 0, stream>>>(h1a, o2, wm2, dp_s1, dp_b1,
                                              dp_s2, dp_b2, h2);

  hipMemsetAsync(accfh, 0, 552960 * sizeof(float), stream);
  conv_fh_k<<<dim3(36, 6, 4), blk, 0, stream>>>(pfea, dc_wfh, accfh);

  msggru_k<<<dim3(36, 6), blk, 0, stream>>>(
      xp, xh, h2, accfh, dp_aw, dp_ab, dp_bw, dp_bb,
      dc_w1, dc_s1, dc_b1, dc_w2, dc_b2, dc_sfh, dc_bfh,
      g_wih1, g_bih1, g_bhh1, g_wih2, g_bih2, g_bhh2, out_m, out_x);
}

// Round 6
// 632.108 us; speedup vs baseline: 3.0721x; 1.1329x over previous
//
#include <hip/hip_runtime.h>
#include <hip/hip_bf16.h>

#define DEV static __device__ __forceinline__

DEV float sigm(float x) { return 1.f / (1.f + __expf(-x)); }

typedef __attribute__((ext_vector_type(8))) short s8;   // 8 bf16 (4 VGPRs)
typedef __attribute__((ext_vector_type(4))) float f4;   // 4 fp32 acc

DEV unsigned short f2bf(float f) {  // RNE float->bf16 bits (finite inputs)
  unsigned u = __float_as_uint(f);
  return (unsigned short)((u + 0x7FFFu + ((u >> 16) & 1u)) >> 16);
}
DEV float bf2f(unsigned short h) { return __uint_as_float(((unsigned)h) << 16); }

// Edge tables from ADJ nonzeros: (src, dst) pairs in np.nonzero order
__constant__ int d_esrc[10] = {0,1,1,1,2,2,3,4,4,5};
__constant__ int d_inc[6][3] = {{1,-1,-1},{0,4,7},{2,6,-1},{5,-1,-1},{3,9,-1},{8,-1,-1}};
__constant__ int d_ne[6] = {1,3,2,1,2,1};

// Deformable tile geometry: 32x8 px, halo 4 -> 16 x 40 data, stride 41.
#define TW 32
#define TH 8
#define SW 41
#define SDC 40
#define SH 16
#define SN 656

// ---------------------------------------------------------------------------
// Weight prep (transpose for block-uniform scalar loads).
//   src: [e][OC][C][3][3]
//   dst: tap_major=0: [e][C][9][OC]   tap_major=1: [e][9][C][OC]
// ---------------------------------------------------------------------------
__global__ void prep_w(const float* __restrict__ src, float* __restrict__ dst,
                       int OC, int C, int tap_major, int total) {
  int i = blockIdx.x * 256 + threadIdx.x;
  if (i >= total) return;
  int t = i % 9; int n = i / 9;
  int c = n % C; n /= C;
  int oc = n % OC; int e = n / OC;
  float v = src[i];
  int inner = tap_major ? (t * C + c) : (c * 9 + t);
  dst[(e * C * 9 + inner) * OC + oc] = v;
}

// ---------------------------------------------------------------------------
// A-fragment prep for offconv1 MFMA: W1[e][27][266][9] -> bf16 hi/lo frags.
// Layout: [e*133+cg][tile(2)][lane(64)][8 hi | 8 lo] shorts (2048/cg-edge).
// k = quad*8+j -> csel=k>>4 (channel 2cg+csel), t=k&15 (tap; >=9 padded 0).
// ---------------------------------------------------------------------------
__global__ void aprep1_k(const float* __restrict__ ow1,
                         unsigned short* __restrict__ dst) {
  int i = blockIdx.x * 256 + threadIdx.x;     // 10*133*2*64 = 170240
  int lane = i & 63;
  int tile = (i >> 6) & 1;
  int cg = (i >> 7) % 133;
  int e = (i >> 7) / 133;
  int m = lane & 15, quad = lane >> 4;
  int oc = tile * 16 + m;
  unsigned short* out = dst + ((e * 133 + cg) * 2 + tile) * 1024 + lane * 16;
#pragma unroll
  for (int j = 0; j < 8; ++j) {
    int k = quad * 8 + j;
    int csel = k >> 4, t = k & 15;
    int c = 2 * cg + csel;
    float w = (oc < 27 && t < 9) ? ow1[((e * 27 + oc) * 266 + c) * 9 + t] : 0.f;
    unsigned short h = f2bf(w);
    float fl = w - bf2f(h);
    out[j] = h;
    out[8 + j] = f2bf(fl);
  }
}

// o1 = bias broadcast; h1a = 0.  total = 2488320 + 1843200
__global__ void init_k(const float* __restrict__ ob, float* __restrict__ o1,
                       float* __restrict__ h1a) {
  int i = blockIdx.x * 256 + threadIdx.x;
  if (i < 2488320) o1[i] = ob[i / 9216];
  else h1a[i - 2488320] = 0.f;
}

// o2 = bias broadcast; h2 = 0.  total = 2488320 + 921600
__global__ void init2_k(const float* __restrict__ ob, float* __restrict__ o2,
                        float* __restrict__ h2) {
  int i = blockIdx.x * 256 + threadIdx.x;
  if (i < 2488320) o2[i] = ob[i / 9216];
  else h2[i - 2488320] = 0.f;
}

// Staging address for deformable halo-4 window (clamped), element i of 16x41.
DEV int stage_goff(int i, int ty0, int tx0) {
  int r = i / SW, cl = i % SW;
  cl = min(cl, SDC - 1);
  int gy = min(max(ty0 - 4 + r, 0), 95);
  int gx = min(max(tx0 - 4 + cl, 0), 95);
  return gy * 96 + gx;
}

// ---------------------------------------------------------------------------
// Offset conv 1 via MFMA. grid (10, 36, 4). Tile 32x8 px, halo-1 zero-pad
// window 10x34, stride 35, 2 channels (K=32 tap-padded) per iteration.
// hi/lo bf16 split => ~fp32 accuracy. Atomic accumulate into bias-inited o1.
// ---------------------------------------------------------------------------
#define OSWB 35
#define OSEC 384
#define OBUF 896

__global__ __launch_bounds__(256) void offconv1_mfma_k(
    const float* __restrict__ pfea, const float* __restrict__ xp,
    const unsigned short* __restrict__ aw, float* __restrict__ o1) {
  __shared__ float sbuf[2][OBUF];
  const int e = blockIdx.x, m = blockIdx.y, z = blockIdx.z;
  const int tid = threadIdx.x;
  const int lane = tid & 63, wv = tid >> 6;
  const int quad = lane >> 4, n16 = lane & 15;
  const int tx0 = (m % 3) * 32, ty0 = (m / 3) * 8;
  const float* xpe = xp + d_esrc[e] * 10 * 9216;
  const int cg_lo = (z * 133) / 4, cg_hi = ((z + 1) * 133) / 4;

  // staging slots: 3 per thread covering 768 window slots (2 sections)
  int g[3]; bool oks[3];
#pragma unroll
  for (int i = 0; i < 3; ++i) {
    int s = tid + i * 256;
    int sec = s / OSEC, off = s - sec * OSEC;
    int r = off / OSWB, cl = off % OSWB;
    int gy = ty0 - 1 + r, gx = tx0 - 1 + cl;
    bool ok = (off < 350) && (cl < 34) && (gy >= 0) && (gy < 96) &&
              (gx >= 0) && (gx < 96);
    oks[i] = ok;
    g[i] = sec * 9216 + (ok ? (gy * 96 + gx) : 0);
  }
  // zero the junk-read tail so padded-tap reads are finite
  if (tid < OBUF - 768) { sbuf[0][768 + tid] = 0.f; sbuf[1][768 + tid] = 0.f; }

  // per-lane k-slot deltas (t may be >=9: junk but in-range; A is 0 there)
  const int tbase = (quad & 1) * 8;
  const int csel = quad >> 1;
  int bdelta[8];
#pragma unroll
  for (int j = 0; j < 8; ++j) {
    int t = tbase + j;
    int dy = t / 3 - 1, dx = t % 3 - 1;
    bdelta[j] = csel * OSEC + dy * OSWB + dx;
  }
  int bidx[4];
#pragma unroll
  for (int nt = 0; nt < 4; ++nt) {
    int r = 2 * wv + (nt >> 1), h = nt & 1;
    bidx[nt] = (r + 1) * OSWB + (h * 16 + n16 + 1);
  }

  f4 acc[4][2] = {};

  int c0 = 2 * cg_lo;
  const float* base = (c0 < 256) ? (pfea + c0 * 9216) : (xpe + (c0 - 256) * 9216);
  float pv0 = oks[0] ? base[g[0]] : 0.f;
  float pv1 = oks[1] ? base[g[1]] : 0.f;
  float pv2 = oks[2] ? base[g[2]] : 0.f;

  int bsel = 0;
  for (int cg = cg_lo; cg < cg_hi; ++cg, bsel ^= 1) {
    float* buf = sbuf[bsel];
    buf[tid] = pv0; buf[tid + 256] = pv1; buf[tid + 512] = pv2;
    if (cg + 1 < cg_hi) {
      int c0n = 2 * (cg + 1);
      const float* nb = (c0n < 256) ? (pfea + c0n * 9216)
                                    : (xpe + (c0n - 256) * 9216);
      pv0 = oks[0] ? nb[g[0]] : 0.f;
      pv1 = oks[1] ? nb[g[1]] : 0.f;
      pv2 = oks[2] ? nb[g[2]] : 0.f;
    }
    const unsigned short* apc = aw + (e * 133 + cg) * 2048 + lane * 16;
    s8 Ah0 = *(const s8*)(apc);
    s8 Al0 = *(const s8*)(apc + 8);
    s8 Ah1 = *(const s8*)(apc + 1024);
    s8 Al1 = *(const s8*)(apc + 1024 + 8);
    __syncthreads();
#pragma unroll
    for (int nt = 0; nt < 4; ++nt) {
      union { s8 v; unsigned short u[8]; } Bh, Bl;
#pragma unroll
      for (int j = 0; j < 8; ++j) {
        float v = buf[bidx[nt] + bdelta[j]];
        unsigned short h = f2bf(v);
        Bh.u[j] = h;
        Bl.u[j] = f2bf(v - bf2f(h));
      }
      acc[nt][0] = __builtin_amdgcn_mfma_f32_16x16x32_bf16(Ah0, Bh.v, acc[nt][0], 0, 0, 0);
      acc[nt][0] = __builtin_amdgcn_mfma_f32_16x16x32_bf16(Ah0, Bl.v, acc[nt][0], 0, 0, 0);
      acc[nt][0] = __builtin_amdgcn_mfma_f32_16x16x32_bf16(Al0, Bh.v, acc[nt][0], 0, 0, 0);
      acc[nt][1] = __builtin_amdgcn_mfma_f32_16x16x32_bf16(Ah1, Bh.v, acc[nt][1], 0, 0, 0);
      acc[nt][1] = __builtin_amdgcn_mfma_f32_16x16x32_bf16(Ah1, Bl.v, acc[nt][1], 0, 0, 0);
      acc[nt][1] = __builtin_amdgcn_mfma_f32_16x16x32_bf16(Al1, Bh.v, acc[nt][1], 0, 0, 0);
    }
  }
  // epilogue: D[m=quad*4+r][n=lane&15]
#pragma unroll
  for (int nt = 0; nt < 4; ++nt) {
    int y = ty0 + 2 * wv + (nt >> 1);
    int xx = tx0 + (nt & 1) * 16 + n16;
    int p = y * 96 + xx;
#pragma unroll
    for (int t2 = 0; t2 < 2; ++t2)
#pragma unroll
      for (int r = 0; r < 4; ++r) {
        int oc = t2 * 16 + quad * 4 + r;
        if (oc < 27)
          atomicAdd(&o1[(e * 27 + oc) * 9216 + p], acc[nt][t2][r]);
      }
  }
}

// ---------------------------------------------------------------------------
// Deformable main conv 1 (LDS bilinear, pair-staged, split-K z=8, atomic).
// grid (10, 36, 8)  [unchanged from r5]
// ---------------------------------------------------------------------------
#define IMG1(c) (((c) < 256) ? (pfea + (c) * 9216) : (xpe + ((c) - 256) * 9216))

__global__ __launch_bounds__(256) void dfmain1_k(
    const float* __restrict__ pfea, const float* __restrict__ xp,
    const float* __restrict__ o1, const float* __restrict__ wm,
    float* __restrict__ hacc) {
  __shared__ float sbuf[2][2 * SN];
  const int e = blockIdx.x, m = blockIdx.y, z = blockIdx.z;
  const int tid = threadIdx.x;
  const int tx = tid % TW, ty = tid / TW;
  const int tx0 = (m % 3) * TW, ty0 = (m / 3) * TH;
  const int y = ty0 + ty, x = tx0 + tx;
  const int p = y * 96 + x;
  const float* xpe = xp + d_esrc[e] * 10 * 9216;
  const int c_lo = (z * 266) / 8, c_hi = ((z + 1) * 266) / 8;

  const int g0 = stage_goff(tid, ty0, tx0);
  const int g1 = stage_goff(tid + 256, ty0, tx0);
  const int g2 = (tid < SN - 512) ? stage_goff(tid + 512, ty0, tx0) : 0;

  int iob[9]; float cw[9][4];
  bool oob = false;
#pragma unroll
  for (int k = 0; k < 9; ++k) {
    float offy = o1[(e * 27 + 2 * k) * 9216 + p];
    float offx = o1[(e * 27 + 2 * k + 1) * 9216 + p];
    float mk = sigm(o1[(e * 27 + 18 + k) * 9216 + p]);
    float py = (float)(y + k / 3 - 1) + offy;
    float px = (float)(x + k % 3 - 1) + offx;
    float fy = floorf(py), fx = floorf(px);
    float wy = py - fy, wx = px - fx;
    int iy = (int)fy, ix = (int)fx;
#pragma unroll
    for (int dy = 0; dy < 2; ++dy)
#pragma unroll
      for (int dx = 0; dx < 2; ++dx) {
        bool ok = (iy + dy >= 0) && (iy + dy < 96) && (ix + dx >= 0) && (ix + dx < 96);
        cw[k][dy * 2 + dx] =
            (ok ? mk : 0.f) * (dy ? wy : (1.f - wy)) * (dx ? wx : (1.f - wx));
      }
    int ir = iy - (ty0 - 4), ic = ix - (tx0 - 4);
    oob |= ((unsigned)ir > (unsigned)(SH - 2)) | ((unsigned)ic > (unsigned)(SDC - 2));
    iob[k] = min(max(ir, 0), SH - 2) * SW + min(max(ic, 0), SDC - 2);
  }

  float acc[20];
#pragma unroll
  for (int oc = 0; oc < 20; ++oc) acc[oc] = 0.f;

  const float* ia = IMG1(c_lo);
  const float* ib = IMG1(min(c_lo + 1, c_hi - 1));
  float pa0 = ia[g0], pa1 = ia[g1], pa2 = (tid < SN - 512) ? ia[g2] : 0.f;
  float pb0 = ib[g0], pb1 = ib[g1], pb2 = (tid < SN - 512) ? ib[g2] : 0.f;

  int bsel = 0;
  for (int c = c_lo; c < c_hi; c += 2, bsel ^= 1) {
    float* buf = sbuf[bsel];
    buf[tid] = pa0; buf[tid + 256] = pa1;
    if (tid < SN - 512) buf[tid + 512] = pa2;
    buf[SN + tid] = pb0; buf[SN + tid + 256] = pb1;
    if (tid < SN - 512) buf[SN + tid + 512] = pb2;
    if (c + 2 < c_hi) {
      const float* na = IMG1(c + 2);
      const float* nb = IMG1(min(c + 3, c_hi - 1));
      pa0 = na[g0]; pa1 = na[g1]; if (tid < SN - 512) pa2 = na[g2];
      pb0 = nb[g0]; pb1 = nb[g1]; if (tid < SN - 512) pb2 = nb[g2];
    }
    __syncthreads();
    {
#pragma unroll
      for (int k = 0; k < 9; ++k) {
        const float* bk = buf + iob[k];
        float sv = cw[k][0] * bk[0] + cw[k][1] * bk[1] +
                   cw[k][2] * bk[SW] + cw[k][3] * bk[SW + 1];
        const float* wc = wm + ((e * 9 + k) * 266 + c) * 20;
#pragma unroll
        for (int oc = 0; oc < 20; ++oc) acc[oc] = fmaf(sv, wc[oc], acc[oc]);
      }
    }
    if (c + 1 < c_hi) {
      const float* bufb = buf + SN;
#pragma unroll
      for (int k = 0; k < 9; ++k) {
        const float* bk = bufb + iob[k];
        float sv = cw[k][0] * bk[0] + cw[k][1] * bk[1] +
                   cw[k][2] * bk[SW] + cw[k][3] * bk[SW + 1];
        const float* wc = wm + ((e * 9 + k) * 266 + c + 1) * 20;
#pragma unroll
        for (int oc = 0; oc < 20; ++oc) acc[oc] = fmaf(sv, wc[oc], acc[oc]);
      }
    }
  }

  if (oob) {
#pragma unroll
    for (int oc = 0; oc < 20; ++oc) acc[oc] = 0.f;
    for (int k = 0; k < 9; ++k) {
      float offy = o1[(e * 27 + 2 * k) * 9216 + p];
      float offx = o1[(e * 27 + 2 * k + 1) * 9216 + p];
      float mk = sigm(o1[(e * 27 + 18 + k) * 9216 + p]);
      float py = (float)(y + k / 3 - 1) + offy;
      float px = (float)(x + k % 3 - 1) + offx;
      float fy = floorf(py), fx = floorf(px);
      float wy = py - fy, wx = px - fx;
      int iy = (int)fy, ix = (int)fx;
      int go[4]; float gw[4];
#pragma unroll
      for (int dy = 0; dy < 2; ++dy)
#pragma unroll
        for (int dx = 0; dx < 2; ++dx) {
          bool ok = (iy + dy >= 0) && (iy + dy < 96) && (ix + dx >= 0) && (ix + dx < 96);
          int yc = min(max(iy + dy, 0), 95), xc = min(max(ix + dx, 0), 95);
          go[dy * 2 + dx] = yc * 96 + xc;
          gw[dy * 2 + dx] =
              (ok ? mk : 0.f) * (dy ? wy : (1.f - wy)) * (dx ? wx : (1.f - wx));
        }
      for (int c = c_lo; c < c_hi; ++c) {
        const float* ptr = IMG1(c);
        float sv = gw[0] * ptr[go[0]] + gw[1] * ptr[go[1]] +
                   gw[2] * ptr[go[2]] + gw[3] * ptr[go[3]];
        const float* wc = wm + ((e * 9 + k) * 266 + c) * 20;
#pragma unroll
        for (int oc = 0; oc < 20; ++oc) acc[oc] = fmaf(sv, wc[oc], acc[oc]);
      }
    }
  }
#pragma unroll
  for (int oc = 0; oc < 20; ++oc)
    atomicAdd(&hacc[(e * 20 + oc) * 9216 + p], acc[oc]);
}

// ---------------------------------------------------------------------------
// Offset conv 2: 3x3 SAME on h1 = relu(s1*h1a+b1) at staging. Split z=2,
// atomic into bias-inited o2. grid (10, 36, 2)
// ---------------------------------------------------------------------------
__global__ __launch_bounds__(256) void offconv2_k(
    const float* __restrict__ h1a, const float* __restrict__ wf,
    const float* __restrict__ s1, const float* __restrict__ b1,
    float* __restrict__ o2) {
  __shared__ float sbuf[2][2 * SN];
  const int e = blockIdx.x, m = blockIdx.y;
  const int c_lo = blockIdx.z * 10;
  const int tid = threadIdx.x;
  const int tx = tid % TW, ty = tid / TW;
  const int tx0 = (m % 3) * TW, ty0 = (m / 3) * TH;
  const int y = ty0 + ty, x = tx0 + tx;
  const int p = y * 96 + x;
  const float* base = h1a + e * 20 * 9216;

  const int g0 = stage_goff(tid, ty0, tx0);
  const int g1 = stage_goff(tid + 256, ty0, tx0);
  const int g2 = (tid < SN - 512) ? stage_goff(tid + 512, ty0, tx0) : 0;

  float vmask[9];
#pragma unroll
  for (int t = 0; t < 9; ++t) {
    int yy = y + t / 3 - 1, xx = x + t % 3 - 1;
    vmask[t] = ((yy >= 0) && (yy < 96) && (xx >= 0) && (xx < 96)) ? 1.f : 0.f;
  }
  const int vbase = (ty + 3) * SW + (tx + 3);

  float acc[27];
#pragma unroll
  for (int oc = 0; oc < 27; ++oc) acc[oc] = 0.f;

  const float* ia = base + c_lo * 9216;
  const float* ib = ia + 9216;
  float pa0 = ia[g0], pa1 = ia[g1], pa2 = (tid < SN - 512) ? ia[g2] : 0.f;
  float pb0 = ib[g0], pb1 = ib[g1], pb2 = (tid < SN - 512) ? ib[g2] : 0.f;

  int bsel = 0;
  for (int c = c_lo; c < c_lo + 10; c += 2, bsel ^= 1) {
    float sa = s1[e * 20 + c], ba = b1[e * 20 + c];
    float sb = s1[e * 20 + c + 1], bb2 = b1[e * 20 + c + 1];
    float* buf = sbuf[bsel];
    buf[tid] = fmaxf(fmaf(sa, pa0, ba), 0.f);
    buf[tid + 256] = fmaxf(fmaf(sa, pa1, ba), 0.f);
    if (tid < SN - 512) buf[tid + 512] = fmaxf(fmaf(sa, pa2, ba), 0.f);
    buf[SN + tid] = fmaxf(fmaf(sb, pb0, bb2), 0.f);
    buf[SN + tid + 256] = fmaxf(fmaf(sb, pb1, bb2), 0.f);
    if (tid < SN - 512) buf[SN + tid + 512] = fmaxf(fmaf(sb, pb2, bb2), 0.f);
    if (c + 2 < c_lo + 10) {
      const float* na = base + (c + 2) * 9216;
      const float* nb = base + (c + 3) * 9216;
      pa0 = na[g0]; pa1 = na[g1]; if (tid < SN - 512) pa2 = na[g2];
      pb0 = nb[g0]; pb1 = nb[g1]; if (tid < SN - 512) pb2 = nb[g2];
    }
    __syncthreads();
#pragma unroll
    for (int cc = 0; cc < 2; ++cc) {
      const float* wc = wf + (e * 20 + c + cc) * 243;
      const float* bp = buf + cc * SN;
#pragma unroll
      for (int t = 0; t < 9; ++t) {
        float v = vmask[t] * bp[vbase + (t / 3) * SW + (t % 3)];
#pragma unroll
        for (int oc = 0; oc < 27; ++oc)
          acc[oc] = fmaf(v, wc[t * 27 + oc], acc[oc]);
      }
    }
  }
#pragma unroll
  for (int oc = 0; oc < 27; ++oc)
    atomicAdd(&o2[(e * 27 + oc) * 9216 + p], acc[oc]);
}

// ---------------------------------------------------------------------------
// Deformable main conv 2: h1 affine+relu at staging; split z=2, atomic raw
// accumulate into zero-inited h2 (s2/b2+relu applied in msggru). grid (10,36,2)
// ---------------------------------------------------------------------------
__global__ __launch_bounds__(256) void dfmain2_k(
    const float* __restrict__ h1a, const float* __restrict__ o2,
    const float* __restrict__ wm, const float* __restrict__ s1,
    const float* __restrict__ b1, float* __restrict__ hout) {
  __shared__ float sbuf[2][2 * SN];
  const int e = blockIdx.x, m = blockIdx.y;
  const int c_lo = blockIdx.z * 10;
  const int tid = threadIdx.x;
  const int tx = tid % TW, ty = tid / TW;
  const int tx0 = (m % 3) * TW, ty0 = (m / 3) * TH;
  const int y = ty0 + ty, x = tx0 + tx;
  const int p = y * 96 + x;
  const float* base = h1a + e * 20 * 9216;

  const int g0 = stage_goff(tid, ty0, tx0);
  const int g1 = stage_goff(tid + 256, ty0, tx0);
  const int g2 = (tid < SN - 512) ? stage_goff(tid + 512, ty0, tx0) : 0;

  int iob[9]; float cw[9][4];
  bool oob = false;
#pragma unroll
  for (int k = 0; k < 9; ++k) {
    float offy = o2[(e * 27 + 2 * k) * 9216 + p];
    float offx = o2[(e * 27 + 2 * k + 1) * 9216 + p];
    float mk = sigm(o2[(e * 27 + 18 + k) * 9216 + p]);
    float py = (float)(y + k / 3 - 1) + offy;
    float px = (float)(x + k % 3 - 1) + offx;
    float fy = floorf(py), fx = floorf(px);
    float wy = py - fy, wx = px - fx;
    int iy = (int)fy, ix = (int)fx;
#pragma unroll
    for (int dy = 0; dy < 2; ++dy)
#pragma unroll
      for (int dx = 0; dx < 2; ++dx) {
        bool ok = (iy + dy >= 0) && (iy + dy < 96) && (ix + dx >= 0) && (ix + dx < 96);
        cw[k][dy * 2 + dx] =
            (ok ? mk : 0.f) * (dy ? wy : (1.f - wy)) * (dx ? wx : (1.f - wx));
      }
    int ir = iy - (ty0 - 4), ic = ix - (tx0 - 4);
    oob |= ((unsigned)ir > (unsigned)(SH - 2)) | ((unsigned)ic > (unsigned)(SDC - 2));
    iob[k] = min(max(ir, 0), SH - 2) * SW + min(max(ic, 0), SDC - 2);
  }

  float acc[10];
#pragma unroll
  for (int oc = 0; oc < 10; ++oc) acc[oc] = 0.f;

  const float* ia = base + c_lo * 9216;
  const float* ib = ia + 9216;
  float pa0 = ia[g0], pa1 = ia[g1], pa2 = (tid < SN - 512) ? ia[g2] : 0.f;
  float pb0 = ib[g0], pb1 = ib[g1], pb2 = (tid < SN - 512) ? ib[g2] : 0.f;

  int bsel = 0;
  for (int c = c_lo; c < c_lo + 10; c += 2, bsel ^= 1) {
    float sa = s1[e * 20 + c], ba = b1[e * 20 + c];
    float sb = s1[e * 20 + c + 1], bb2 = b1[e * 20 + c + 1];
    float* buf = sbuf[bsel];
    buf[tid] = fmaxf(fmaf(sa, pa0, ba), 0.f);
    buf[tid + 256] = fmaxf(fmaf(sa, pa1, ba), 0.f);
    if (tid < SN - 512) buf[tid + 512] = fmaxf(fmaf(sa, pa2, ba), 0.f);
    buf[SN + tid] = fmaxf(fmaf(sb, pb0, bb2), 0.f);
    buf[SN + tid + 256] = fmaxf(fmaf(sb, pb1, bb2), 0.f);
    if (tid < SN - 512) buf[SN + tid + 512] = fmaxf(fmaf(sb, pb2, bb2), 0.f);
    if (c + 2 < c_lo + 10) {
      const float* na = base + (c + 2) * 9216;
      const float* nb = base + (c + 3) * 9216;
      pa0 = na[g0]; pa1 = na[g1]; if (tid < SN - 512) pa2 = na[g2];
      pb0 = nb[g0]; pb1 = nb[g1]; if (tid < SN - 512) pb2 = nb[g2];
    }
    __syncthreads();
#pragma unroll
    for (int cc = 0; cc < 2; ++cc) {
      const float* bp = buf + cc * SN;
#pragma unroll
      for (int k = 0; k < 9; ++k) {
        const float* bk = bp + iob[k];
        float sv = cw[k][0] * bk[0] + cw[k][1] * bk[1] +
                   cw[k][2] * bk[SW] + cw[k][3] * bk[SW + 1];
        const float* wc = wm + ((e * 9 + k) * 20 + c + cc) * 10;
#pragma unroll
        for (int oc = 0; oc < 10; ++oc) acc[oc] = fmaf(sv, wc[oc], acc[oc]);
      }
    }
  }

  if (oob) {
#pragma unroll
    for (int oc = 0; oc < 10; ++oc) acc[oc] = 0.f;
    for (int k = 0; k < 9; ++k) {
      float offy = o2[(e * 27 + 2 * k) * 9216 + p];
      float offx = o2[(e * 27 + 2 * k + 1) * 9216 + p];
      float mk = sigm(o2[(e * 27 + 18 + k) * 9216 + p]);
      float py = (float)(y + k / 3 - 1) + offy;
      float px = (float)(x + k % 3 - 1) + offx;
      float fy = floorf(py), fx = floorf(px);
      float wy = py - fy, wx = px - fx;
      int iy = (int)fy, ix = (int)fx;
      int go[4]; float gw[4];
#pragma unroll
      for (int dy = 0; dy < 2; ++dy)
#pragma unroll
        for (int dx = 0; dx < 2; ++dx) {
          bool ok = (iy + dy >= 0) && (iy + dy < 96) && (ix + dx >= 0) && (ix + dx < 96);
          int yc = min(max(iy + dy, 0), 95), xc = min(max(ix + dx, 0), 95);
          go[dy * 2 + dx] = yc * 96 + xc;
          gw[dy * 2 + dx] =
              (ok ? mk : 0.f) * (dy ? wy : (1.f - wy)) * (dx ? wx : (1.f - wx));
        }
      for (int c = c_lo; c < c_lo + 10; ++c) {
        float sc = s1[e * 20 + c], bc = b1[e * 20 + c];
        const float* ptr = base + c * 9216;
        float v0 = fmaxf(fmaf(sc, ptr[go[0]], bc), 0.f);
        float v1 = fmaxf(fmaf(sc, ptr[go[1]], bc), 0.f);
        float v2 = fmaxf(fmaf(sc, ptr[go[2]], bc), 0.f);
        float v3 = fmaxf(fmaf(sc, ptr[go[3]], bc), 0.f);
        float sv = gw[0] * v0 + gw[1] * v1 + gw[2] * v2 + gw[3] * v3;
        const float* wc = wm + ((e * 9 + k) * 20 + c) * 10;
#pragma unroll
        for (int oc = 0; oc < 10; ++oc) acc[oc] = fmaf(sv, wc[oc], acc[oc]);
      }
    }
  }
#pragma unroll
  for (int oc = 0; oc < 10; ++oc)
    atomicAdd(&hout[(e * 10 + oc) * 9216 + p], acc[oc]);
}

// 1x1 conv p_fea (256ch) -> accfh[j][10][9216], split-K atomic. grid (36,6,4)
__global__ __launch_bounds__(256) void conv_fh_k(
    const float* __restrict__ pfea, const float* __restrict__ wfh,
    float* __restrict__ accfh) {
  const int j = blockIdx.y;
  const int z = blockIdx.z;
  const int p = blockIdx.x * 256 + threadIdx.x;
  const int c_lo = z * 64;
  float acc[10];
#pragma unroll
  for (int c = 0; c < 10; ++c) acc[c] = 0.f;
  for (int ci = c_lo; ci < c_lo + 64; ci += 4) {
    float pv0 = pfea[ci * 9216 + p];
    float pv1 = pfea[(ci + 1) * 9216 + p];
    float pv2 = pfea[(ci + 2) * 9216 + p];
    float pv3 = pfea[(ci + 3) * 9216 + p];
#pragma unroll
    for (int c = 0; c < 10; ++c) {
      acc[c] = fmaf(pv0, wfh[(j * 10 + c) * 256 + ci], acc[c]);
      acc[c] = fmaf(pv1, wfh[(j * 10 + c) * 256 + ci + 1], acc[c]);
      acc[c] = fmaf(pv2, wfh[(j * 10 + c) * 256 + ci + 2], acc[c]);
      acc[c] = fmaf(pv3, wfh[(j * 10 + c) * 256 + ci + 3], acc[c]);
    }
  }
#pragma unroll
  for (int c = 0; c < 10; ++c)
    atomicAdd(&accfh[(j * 10 + c) * 9216 + p], acc[c]);
}

// ---------------------------------------------------------------------------
// Fused node-message + GRU stage; applies h2 affine (s2,b2)+relu inline.
// grid (36, 6)
// ---------------------------------------------------------------------------
__global__ __launch_bounds__(256) void msggru_k(
    const float* __restrict__ xp, const float* __restrict__ xh,
    const float* __restrict__ h2, const float* __restrict__ accfh,
    const float* __restrict__ s2, const float* __restrict__ b2g,
    const float* __restrict__ aw, const float* __restrict__ ab,
    const float* __restrict__ bw, const float* __restrict__ bb,
    const float* __restrict__ w1, const float* __restrict__ s1,
    const float* __restrict__ b1, const float* __restrict__ w2,
    const float* __restrict__ b2, const float* __restrict__ sfh,
    const float* __restrict__ bfh,
    const float* __restrict__ wih1, const float* __restrict__ bih1,
    const float* __restrict__ bhh1, const float* __restrict__ wih2,
    const float* __restrict__ bih2, const float* __restrict__ bhh2,
    float* __restrict__ out_m, float* __restrict__ out_x) {
  const int j = blockIdx.y;
  const int p = blockIdx.x * 256 + threadIdx.x;
  float xj[10];
#pragma unroll
  for (int c = 0; c < 10; ++c) xj[c] = xp[(j * 10 + c) * 9216 + p];
  float xpp[10];
  int ne = d_ne[j];
  for (int ei = 0; ei < ne; ++ei) {
    int e = d_inc[j][ei];
    int a2 = d_esrc[e];
    float sA = ab[e];
#pragma unroll
    for (int c = 0; c < 10; ++c)
      sA = fmaf(xp[(a2 * 10 + c) * 9216 + p], aw[e * 10 + c], sA);
    float sB = bb[e];
#pragma unroll
    for (int c = 0; c < 10; ++c) sB = fmaf(xj[c], bw[e * 10 + c], sB);
    float f = (1.f - sigm(sA)) * sigm(sB);
#pragma unroll
    for (int c = 0; c < 10; ++c) {
      float raw = h2[(e * 10 + c) * 9216 + p];
      float hv = fmaxf(fmaf(s2[e * 10 + c], raw, b2g[e * 10 + c]), 0.f);
      float mm = f * hv;
      xpp[c] = (ei == 0) ? mm : fmaxf(xpp[c], mm);
    }
  }
  const float* hf = xh + ((j < 4) ? 0 : 1) * 10 * 9216;
  float cat[20];
#pragma unroll
  for (int c = 0; c < 10; ++c) cat[c] = hf[c * 9216 + p];
#pragma unroll
  for (int c = 0; c < 10; ++c) cat[10 + c] = xj[c];
  float at = b2[j];
#pragma unroll
  for (int oc = 0; oc < 20; ++oc) {
    float t = 0.f;
#pragma unroll
    for (int c = 0; c < 20; ++c)
      t = fmaf(cat[c], w1[(j * 20 + oc) * 20 + c], t);
    float av = fmaxf(s1[j * 20 + oc] * t + b1[j * 20 + oc], 0.f);
    at = fmaf(av, w2[j * 20 + oc], at);
  }
  at = sigm(at);
  float msg[10];
#pragma unroll
  for (int c = 0; c < 10; ++c) {
    float xhp = fmaxf(sfh[j * 10 + c] * (at * accfh[(j * 10 + c) * 9216 + p]) +
                          bfh[j * 10 + c], 0.f);
    msg[c] = xpp[c] + xhp;
    out_m[(j * 10 + c) * 9216 + p] = msg[c];
  }
  float gi[30];
#pragma unroll
  for (int r = 0; r < 30; ++r) gi[r] = bih1[j * 30 + r];
#pragma unroll
  for (int c = 0; c < 10; ++c) {
    float v = xj[c];
#pragma unroll
    for (int r = 0; r < 30; ++r)
      gi[r] = fmaf(v, wih1[(j * 30 + r) * 20 + c], gi[r]);
  }
#pragma unroll
  for (int c = 0; c < 10; ++c) {
    float v = msg[c];
#pragma unroll
    for (int r = 0; r < 30; ++r)
      gi[r] = fmaf(v, wih1[(j * 30 + r) * 20 + 10 + c], gi[r]);
  }
  float h1v[10];
#pragma unroll
  for (int c = 0; c < 10; ++c) {
    float r = sigm(gi[c] + bhh1[j * 30 + c]);
    float z = sigm(gi[10 + c] + bhh1[j * 30 + 10 + c]);
    float n = tanhf(gi[20 + c] + r * bhh1[j * 30 + 20 + c]);
    h1v[c] = (1.f - z) * n;
  }
  float g2v[30];
#pragma unroll
  for (int r = 0; r < 30; ++r) g2v[r] = bih2[j * 30 + r];
#pragma unroll
  for (int c = 0; c < 10; ++c) {
    float v = h1v[c];
#pragma unroll
    for (int r = 0; r < 30; ++r)
      g2v[r] = fmaf(v, wih2[(j * 30 + r) * 10 + c], g2v[r]);
  }
#pragma unroll
  for (int c = 0; c < 10; ++c) {
    float r = sigm(g2v[c] + bhh2[j * 30 + c]);
    float z = sigm(g2v[10 + c] + bhh2[j * 30 + 10 + c]);
    float n = tanhf(g2v[20 + c] + r * bhh2[j * 30 + 20 + c]);
    out_x[(j * 10 + c) * 9216 + p] = (1.f - z) * n;
  }
}

extern "C" void kernel_launch(void* const* d_in, const int* in_sizes, int n_in,
                              void* d_out, int out_size, void* d_ws, size_t ws_size,
                              hipStream_t stream) {
  const float* pfea   = (const float*)d_in[0];
  const float* xp     = (const float*)d_in[1];
  const float* xh     = (const float*)d_in[2];
  const float* dp_ow1 = (const float*)d_in[3];
  const float* dp_ob1 = (const float*)d_in[4];
  const float* dp_w1  = (const float*)d_in[5];
  const float* dp_s1  = (const float*)d_in[6];
  const float* dp_b1  = (const float*)d_in[7];
  const float* dp_ow2 = (const float*)d_in[8];
  const float* dp_ob2 = (const float*)d_in[9];
  const float* dp_w2  = (const float*)d_in[10];
  const float* dp_s2  = (const float*)d_in[11];
  const float* dp_b2  = (const float*)d_in[12];
  const float* dp_aw  = (const float*)d_in[13];
  const float* dp_ab  = (const float*)d_in[14];
  const float* dp_bw  = (const float*)d_in[15];
  const float* dp_bb  = (const float*)d_in[16];
  const float* dc_w1  = (const float*)d_in[17];
  const float* dc_s1  = (const float*)d_in[18];
  const float* dc_b1  = (const float*)d_in[19];
  const float* dc_w2  = (const float*)d_in[20];
  const float* dc_b2  = (const float*)d_in[21];
  const float* dc_wfh = (const float*)d_in[22];
  const float* dc_sfh = (const float*)d_in[23];
  const float* dc_bfh = (const float*)d_in[24];
  const float* g_wih1 = (const float*)d_in[25];
  const float* g_bih1 = (const float*)d_in[26];
  const float* g_bhh1 = (const float*)d_in[28];
  const float* g_wih2 = (const float*)d_in[29];
  const float* g_bih2 = (const float*)d_in[30];
  const float* g_bhh2 = (const float*)d_in[32];

  float* ws = (float*)d_ws;
  // Region 0 (1,474,560 floats, multi-use):
  //   phase 1: aw1 = bf16 A-frags for offconv1 (2,723,840 shorts = 1,361,920 f)
  //   phase 2: accfh [0, 552960) + h2 [552960, 1474560)
  unsigned short* aw1 = (unsigned short*)ws;
  float* accfh = ws;
  float* h2    = ws + 552960;
  float* wf2 = ws + 1474560;    // 48600
  float* wm1 = wf2 + 48600;     // 478800
  float* wm2 = wm1 + 478800;    // 18000
  float* o1  = wm2 + 18000;     // 2488320 (o2 aliases after dfmain1)
  float* o2  = o1;
  float* h1a = o1 + 2488320;    // 1843200
  // total: 6,351,480 floats = 25.4 MB

  float* out_x = (float*)d_out;        // xp_out: 6*10*9216
  float* out_m = out_x + 552960;       // msgs:   6*10*9216

  prep_w<<<dim3(190), 256, 0, stream>>>(dp_ow2, wf2, 27, 20, 0, 48600);
  prep_w<<<dim3(1871), 256, 0, stream>>>(dp_w1, wm1, 20, 266, 1, 478800);
  prep_w<<<dim3(71), 256, 0, stream>>>(dp_w2, wm2, 10, 20, 1, 18000);
  aprep1_k<<<dim3(665), 256, 0, stream>>>(dp_ow1, aw1);

  init_k<<<dim3(16920), 256, 0, stream>>>(dp_ob1, o1, h1a);

  dim3 blk(256);
  offconv1_mfma_k<<<dim3(10, 36, 4), blk, 0, stream>>>(pfea, xp, aw1, o1);
  dfmain1_k<<<dim3(10, 36, 8), blk, 0, stream>>>(pfea, xp, o1, wm1, h1a);

  init2_k<<<dim3(13320), 256, 0, stream>>>(dp_ob2, o2, h2);
  offconv2_k<<<dim3(10, 36, 2), blk, 0, stream>>>(h1a, wf2, dp_s1, dp_b1, o2);
  dfmain2_k<<<dim3(10, 36, 2), blk, 0, stream>>>(h1a, o2, wm2, dp_s1, dp_b1, h2);

  hipMemsetAsync(accfh, 0, 552960 * sizeof(float), stream);
  conv_fh_k<<<dim3(36, 6, 4), blk, 0, stream>>>(pfea, dc_wfh, accfh);

  msggru_k<<<dim3(36, 6), blk, 0, stream>>>(
      xp, xh, h2, accfh, dp_s2, dp_b2, dp_aw, dp_ab, dp_bw, dp_bb,
      dc_w1, dc_s1, dc_b1, dc_w2, dc_b2, dc_sfh, dc_bfh,
      g_wih1, g_bih1, g_bhh1, g_wih2, g_bih2, g_bhh2, out_m, out_x);
}